// Round 7
// baseline (541.771 us; speedup 1.0000x reference)
//
#include <hip/hip_runtime.h>

typedef _Float16 f16;
typedef _Float16 half8 __attribute__((ext_vector_type(8)));
typedef _Float16 half4 __attribute__((ext_vector_type(4)));
typedef float floatx4 __attribute__((ext_vector_type(4)));

#define MFMA16(a, b, c) __builtin_amdgcn_mfma_f32_16x16x32_f16(a, b, c, 0, 0, 0)

// async global->LDS, 16B per lane; LDS side = wave-uniform base + lane*16
__device__ __forceinline__ void gload16(const void* g, void* l) {
    __builtin_amdgcn_global_load_lds((const __attribute__((address_space(1))) void*)g,
                                     (__attribute__((address_space(3))) void*)l, 16, 0, 0);
}

// ---------------------------------------------------------------------------
// Kernel 0: convert query [16.8M], W_in [262144], W_out [524288] fp32 -> fp16
// ---------------------------------------------------------------------------
__global__ __launch_bounds__(256) void k_cvt(const float* __restrict__ query,
                                             const float* __restrict__ Wi,
                                             const float* __restrict__ Wo,
                                             f16* __restrict__ q16,
                                             f16* __restrict__ W16)
{
    int i = blockIdx.x * 256 + threadIdx.x;   // float4 index, 4390912 total
    const float4* src;
    f16* dst;
    if (i < 4194304) { src = (const float4*)query + i; dst = q16 + (size_t)i * 4; }
    else if (i < 4259840) { int j = i - 4194304; src = (const float4*)Wi + j; dst = W16 + (size_t)j * 4; }
    else { int j = i - 4259840; src = (const float4*)Wo + j; dst = W16 + 262144 + (size_t)j * 4; }
    float4 v = *src;
    half4 h = {(f16)v.x, (f16)v.y, (f16)v.z, (f16)v.w};
    *reinterpret_cast<half4*>(dst) = h;
}

// ---------------------------------------------------------------------------
// Kernel 1: q = q16 @ W16^T (fp16 gl_lds GEMM, BK=64, 128x128 tile).
// 1D grid 1024 with XCD swizzle. Double-buffered 1-barrier K-loop.
// ---------------------------------------------------------------------------
__global__ __launch_bounds__(256) void k_qin(const f16* __restrict__ q16,
                                             const f16* __restrict__ W16,
                                             f16* __restrict__ comb,
                                             f16* __restrict__ qT)
{
    __shared__ char sm[65536];
    const int tid = threadIdx.x, lane = tid & 63, w = tid >> 6;
    const int l15 = lane & 15, quad = lane >> 4;
    const int id = blockIdx.x, xcd = id & 7, u = id >> 3;
    const int mbase = (xcd * 32 + (u >> 2)) * 128;   // m-tile 0..255
    const int nbase = (u & 3) * 128;                 // n-tile 0..3
    const int wm = (w & 1) * 64, wn = (w >> 1) * 64;
    const int ia = wm >> 4, jb = wn >> 4;

    floatx4 acc[4][4];
#pragma unroll
    for (int i = 0; i < 4; ++i)
#pragma unroll
        for (int j = 0; j < 4; ++j) acc[i][j] = (floatx4)0.f;

    auto STAGE = [&](int k0, int bsel) {
        f16* At = (f16*)(sm + bsel * 32768);
        f16* Bt = At + 8192;
#pragma unroll
        for (int jr = 0; jr < 4; ++jr) {
            int bi = jr * 4 + w, i2 = bi >> 1, s = bi & 1;
            gload16(q16 + (size_t)(mbase + i2 * 16 + l15) * 512 + k0 + s * 32 + quad * 8, At + bi * 512);
            gload16(W16 + (size_t)(nbase + i2 * 16 + l15) * 512 + k0 + s * 32 + quad * 8, Bt + bi * 512);
        }
    };

    STAGE(0, 0);
    __syncthreads();   // buf0 ready
    for (int it = 0; it < 8; ++it) {
        const int cur = it & 1;
        if (it < 7) STAGE((it + 1) * 64, cur ^ 1);   // prefetch overlaps MFMAs
        f16* At = (f16*)(sm + cur * 32768);
        f16* Bt = At + 8192;
#pragma unroll
        for (int s = 0; s < 2; ++s) {
            half8 a[4], bf[4];
#pragma unroll
            for (int i = 0; i < 4; ++i)
                a[i] = *reinterpret_cast<half8*>(At + ((ia + i) * 2 + s) * 512 + lane * 8);
#pragma unroll
            for (int j = 0; j < 4; ++j)
                bf[j] = *reinterpret_cast<half8*>(Bt + ((jb + j) * 2 + s) * 512 + lane * 8);
#pragma unroll
            for (int i = 0; i < 4; ++i)
#pragma unroll
                for (int j = 0; j < 4; ++j)
                    acc[i][j] = MFMA16(a[i], bf[j], acc[i][j]);
        }
        __syncthreads();   // prefetch drained + all waves done with cur
    }
    const int bb = mbase >> 11, tb = mbase & 2047;
    f16* ct = (f16*)sm;   // phase A: row-major [128][136] (aliases dead staging bufs)
#pragma unroll
    for (int i = 0; i < 4; ++i)
#pragma unroll
        for (int j = 0; j < 4; ++j)
#pragma unroll
            for (int r = 0; r < 4; ++r)
                ct[(wm + i * 16 + quad * 4 + r) * 136 + wn + j * 16 + l15] = (f16)acc[i][j][r];
    __syncthreads();
#pragma unroll
    for (int it = 0; it < 8; ++it) {
        int c = it * 256 + tid, r = c >> 4, c8 = (c & 15) << 3;
        *reinterpret_cast<half8*>(comb + (size_t)(mbase + r) * 1024 + 512 + nbase + c8) =
            *reinterpret_cast<half8*>(ct + r * 136 + c8);
    }
    __syncthreads();
    // phase B: column-major [128 cols][136] — vectorized half4 dumps from acc
#pragma unroll
    for (int i = 0; i < 4; ++i)
#pragma unroll
        for (int j = 0; j < 4; ++j) {
            half4 h = {(f16)acc[i][j][0], (f16)acc[i][j][1], (f16)acc[i][j][2], (f16)acc[i][j][3]};
            *reinterpret_cast<half4*>(ct + (wn + j * 16 + l15) * 136 + wm + i * 16 + quad * 4) = h;
        }
    __syncthreads();
    // qT writes: 16 lanes share a d-row -> 256 B contiguous global segments
#pragma unroll
    for (int it = 0; it < 8; ++it) {
        int c = it * 256 + tid, dd = c >> 4, tc = (c & 15) << 3;
        *reinterpret_cast<half8*>(qT + ((size_t)bb * 512 + nbase + dd) * 2048 + tb + tc) =
            *reinterpret_cast<half8*>(ct + dd * 136 + tc);
    }
}

// ---------------------------------------------------------------------------
// Kernel 2 (NEW): fused S = q@q^T + ONLINE softmax. Eliminates the fp32 S
// matrix from HBM entirely (r2-r6 evidence: S round-trip = ~400MB HBM).
// Block = (b, mt-strip, 64-row half): streams K-tiles nt=0..mt through
// registers; maintains running row max m and sum l (flash recurrence);
// writes P' = exp(S - m_run) fp16 (dense, <=1), per-tile rescale factors
// R[b][nt][row] = exp(m_prev - m_new), and final L[b][row] = l.
// Heavy strips first (id>>4: mt descending); id&15 = b -> batch/XCD pin.
// ---------------------------------------------------------------------------
__global__ __launch_bounds__(256) void k_sgemmsm(const f16* __restrict__ comb,
                                                 f16* __restrict__ Pd,
                                                 float* __restrict__ Rt,
                                                 float* __restrict__ Lt)
{
    __shared__ char sm[51200];   // 2 x 24576 staging dbuf + redm 1KB + reds 1KB
    const int tid = threadIdx.x, lane = tid & 63, w = tid >> 6;
    const int l15 = lane & 15, quad = lane >> 4;
    const int id = blockIdx.x;
    const int b = id & 15, s_ = id >> 4;          // s_ = 0..31
    const int mt = 15 - (s_ >> 1), h = s_ & 1;    // heavy-first
    const int qrow0 = mt * 128 + h * 64;
    const int tb0 = mt * (mt + 1) / 2;
    const f16* qa = comb + ((size_t)b * 2048 + qrow0) * 1024 + 512;
    float* redm = (float*)(sm + 49152);   // [4 waves][64 rows]
    float* reds = (float*)(sm + 50176);

    float m_run[4][4], l_run[4][4];
#pragma unroll
    for (int i = 0; i < 4; ++i)
#pragma unroll
        for (int r = 0; r < 4; ++r) { m_run[i][r] = -1e38f; l_run[i][r] = 0.f; }

    for (int nt = 0; nt <= mt; ++nt) {
        const f16* qb = comb + ((size_t)b * 2048 + nt * 128) * 1024 + 512;
        floatx4 acc[4][2];
#pragma unroll
        for (int i = 0; i < 4; ++i)
#pragma unroll
            for (int j = 0; j < 2; ++j) acc[i][j] = (floatx4)0.f;

        // stage A 64x64 (8 blocks) + B 128x64 (16 blocks) for K-chunk k0
        auto STAGE = [&](int k0, int bsel) {
            f16* At = (f16*)(sm + bsel * 24576);
            f16* Bt = At + 4096;
#pragma unroll
            for (int jr = 0; jr < 2; ++jr) {
                int ab = jr * 4 + w, i2 = ab >> 1, sa = ab & 1;
                gload16(qa + (size_t)(i2 * 16 + l15) * 1024 + k0 + sa * 32 + quad * 8, At + ab * 512);
            }
#pragma unroll
            for (int jr = 0; jr < 4; ++jr) {
                int bi = jr * 4 + w, i2 = bi >> 1, sb = bi & 1;
                gload16(qb + (size_t)(i2 * 16 + l15) * 1024 + k0 + sb * 32 + quad * 8, Bt + bi * 512);
            }
        };

        STAGE(0, 0);
        __syncthreads();
        for (int it = 0; it < 8; ++it) {
            const int cur = it & 1;
            if (it < 7) STAGE((it + 1) * 64, cur ^ 1);
            f16* At = (f16*)(sm + cur * 24576);
            f16* Bt = At + 4096;
#pragma unroll
            for (int s = 0; s < 2; ++s) {
                half8 a[4], bf[2];
#pragma unroll
                for (int i = 0; i < 4; ++i)
                    a[i] = *reinterpret_cast<half8*>(At + (i * 2 + s) * 512 + lane * 8);
#pragma unroll
                for (int j = 0; j < 2; ++j)
                    bf[j] = *reinterpret_cast<half8*>(Bt + ((w * 2 + j) * 2 + s) * 512 + lane * 8);
#pragma unroll
                for (int i = 0; i < 4; ++i)
#pragma unroll
                    for (int j = 0; j < 2; ++j)
                        acc[i][j] = MFMA16(a[i], bf[j], acc[i][j]);
            }
            __syncthreads();
        }

        // ---- online softmax over this 64x128 tile ----
        const bool diag = (nt == mt);
        const int rb64 = h * 64;
        float rfv[4][4], sum_p[4][4];
        f16* ct = (f16*)sm;   // [64][136], aliases dead staging buf0

        // per-row tile max (masked), reduce over l15 then cross-wave via LDS
#pragma unroll
        for (int i = 0; i < 4; ++i)
#pragma unroll
            for (int r = 0; r < 4; ++r) {
                float v0 = acc[i][0][r], v1 = acc[i][1][r];
                if (diag) {
                    int rl = rb64 + i * 16 + quad * 4 + r;
                    if (w * 32 + l15 >= rl)      v0 = -1e38f;
                    if (w * 32 + 16 + l15 >= rl) v1 = -1e38f;
                }
                float mm = fmaxf(v0, v1);
                mm = fmaxf(mm, __shfl_xor(mm, 1));
                mm = fmaxf(mm, __shfl_xor(mm, 2));
                mm = fmaxf(mm, __shfl_xor(mm, 4));
                mm = fmaxf(mm, __shfl_xor(mm, 8));
                sum_p[i][r] = mm;   // stash wave-partial max
            }
        if (l15 == 0)
#pragma unroll
            for (int i = 0; i < 4; ++i)
#pragma unroll
                for (int r = 0; r < 4; ++r)
                    redm[w * 64 + i * 16 + quad * 4 + r] = sum_p[i][r];
        __syncthreads();
#pragma unroll
        for (int i = 0; i < 4; ++i)
#pragma unroll
            for (int r = 0; r < 4; ++r) {
                int row = i * 16 + quad * 4 + r;
                float mm = fmaxf(fmaxf(redm[row], redm[64 + row]),
                                 fmaxf(redm[128 + row], redm[192 + row]));
                float mnew = fmaxf(m_run[i][r], mm);
                float rf = __expf(m_run[i][r] - mnew);
                m_run[i][r] = mnew;
                rfv[i][r] = rf;
                if (w == 0 && l15 == 0)
                    Rt[((size_t)b * 16 + nt) * 2048 + qrow0 + row] = rf;
            }
        // exp, P'->ct, row partial sums
#pragma unroll
        for (int i = 0; i < 4; ++i)
#pragma unroll
            for (int r = 0; r < 4; ++r) {
                int rl = rb64 + i * 16 + quad * 4 + r;
                float ssum = 0.f;
#pragma unroll
                for (int j = 0; j < 2; ++j) {
                    bool valid = !diag || (w * 32 + j * 16 + l15 < rl);
                    float e = valid ? __expf(acc[i][j][r] - m_run[i][r]) : 0.f;
                    ssum += e;
                    ct[(i * 16 + quad * 4 + r) * 136 + w * 32 + j * 16 + l15] = (f16)e;
                }
                ssum += __shfl_xor(ssum, 1);
                ssum += __shfl_xor(ssum, 2);
                ssum += __shfl_xor(ssum, 4);
                ssum += __shfl_xor(ssum, 8);
                sum_p[i][r] = ssum;
            }
        if (l15 == 0)
#pragma unroll
            for (int i = 0; i < 4; ++i)
#pragma unroll
                for (int r = 0; r < 4; ++r)
                    reds[w * 64 + i * 16 + quad * 4 + r] = sum_p[i][r];
        __syncthreads();
#pragma unroll
        for (int i = 0; i < 4; ++i)
#pragma unroll
            for (int r = 0; r < 4; ++r) {
                int row = i * 16 + quad * 4 + r;
                float ts = (reds[row] + reds[64 + row]) + (reds[128 + row] + reds[192 + row]);
                l_run[i][r] = l_run[i][r] * rfv[i][r] + ts;
            }
        // P' tile rows [h*64, h*64+64) -> dense fp16 [b][tile][128][128]
        f16* Pt = Pd + ((size_t)(b * 136 + tb0 + nt) << 14) + (size_t)rb64 * 128;
#pragma unroll
        for (int itp = 0; itp < 4; ++itp) {
            int c = itp * 256 + tid, r_ = c >> 4, c8 = (c & 15) << 3;
            *reinterpret_cast<half8*>(Pt + r_ * 128 + c8) =
                *reinterpret_cast<half8*>(ct + r_ * 136 + c8);
        }
        __syncthreads();   // ct reads done before next tile re-stages buf0
    }
    if (w == 0 && l15 == 0)
#pragma unroll
        for (int i = 0; i < 4; ++i)
#pragma unroll
            for (int r = 0; r < 4; ++r)
                Lt[(size_t)b * 2048 + qrow0 + i * 16 + quad * 4 + r] = l_run[i][r];
}

// ---------------------------------------------------------------------------
// Kernel 4: mix = P' @ q with flash rescale. Between K-tiles, acc is scaled
// by R[b][tt][row] (maps per-row onto C layout row = quad*4+r); epilogue
// applies 1/l (0 for global row 0) -> softmax normalization for free.
// Uniform-work pairing (mt=p with 15-p) + double-buffered 1-barrier pipeline.
// ---------------------------------------------------------------------------
__global__ __launch_bounds__(256) void k_pv(const f16* __restrict__ Pd,
                                            const f16* __restrict__ qT,
                                            f16* __restrict__ comb,
                                            const float* __restrict__ Rt,
                                            const float* __restrict__ Lt)
{
    __shared__ char sm[65536];
    const int tid = threadIdx.x, lane = tid & 63, w = tid >> 6;
    const int l15 = lane & 15, quad = lane >> 4;
    const int wm = (w & 1) * 64, wn = (w >> 1) * 64;
    const int ia = wm >> 4, jb = wn >> 4;
    const int id = blockIdx.x;
    const int p = id & 7, nb = (id >> 3) & 3, b = id >> 5;
    const f16* Pdb = Pd + ((size_t)b * 136 << 14);
    const f16* qTb = qT + ((size_t)b * 512 + nb * 128) * 2048;

    for (int t = 0; t < 2; ++t) {
        const int mt = t ? (15 - p) : p;
        const int tb0 = mt * (mt + 1) / 2;
        const int kit = (mt + 1) * 2;

        floatx4 acc[4][4];
#pragma unroll
        for (int i = 0; i < 4; ++i)
#pragma unroll
            for (int j = 0; j < 4; ++j) acc[i][j] = (floatx4)0.f;

        auto STAGE = [&](int it, int bsel) {
            f16* At = (f16*)(sm + bsel * 32768);
            f16* Bt = At + 8192;
            const int k0 = it * 64;
#pragma unroll
            for (int jr = 0; jr < 4; ++jr) {
                int bi = jr * 4 + w, i2 = bi >> 1, s = bi & 1;
                gload16(Pdb + ((size_t)(tb0 + (k0 >> 7)) << 14) + (size_t)(i2 * 16 + l15) * 128
                            + (k0 & 64) + s * 32 + quad * 8,
                        At + bi * 512);
                gload16(qTb + (size_t)(i2 * 16 + l15) * 2048 + k0 + s * 32 + quad * 8, Bt + bi * 512);
            }
        };

        STAGE(0, 0);
        __syncthreads();   // buf0 ready
        for (int it = 0; it < kit; ++it) {
            const int cur = it & 1;
            if (it + 1 < kit) STAGE(it + 1, cur ^ 1);   // prefetch overlaps compute
            if (it > 0 && (it & 1) == 0) {
                // entering tile tt: acc (tiles < tt) rescaled by exp(m_{tt-1}-m_tt)
                const int tt = it >> 1;
                const float* rbp = Rt + ((size_t)b * 16 + tt) * 2048 + mt * 128 + wm;
#pragma unroll
                for (int i = 0; i < 4; ++i) {
                    floatx4 rv = *reinterpret_cast<const floatx4*>(rbp + i * 16 + quad * 4);
#pragma unroll
                    for (int j = 0; j < 4; ++j)
                        acc[i][j] *= rv;
                }
            }
            f16* At = (f16*)(sm + cur * 32768);
            f16* Bt = At + 8192;
#pragma unroll
            for (int s = 0; s < 2; ++s) {
                half8 a[4], bf[4];
#pragma unroll
                for (int i = 0; i < 4; ++i)
                    a[i] = *reinterpret_cast<half8*>(At + ((ia + i) * 2 + s) * 512 + lane * 8);
#pragma unroll
                for (int j = 0; j < 4; ++j)
                    bf[j] = *reinterpret_cast<half8*>(Bt + ((jb + j) * 2 + s) * 512 + lane * 8);
#pragma unroll
                for (int i = 0; i < 4; ++i)
#pragma unroll
                    for (int j = 0; j < 4; ++j)
                        acc[i][j] = MFMA16(a[i], bf[j], acc[i][j]);
            }
            __syncthreads();
        }

        // epilogue: apply 1/l, bounce via ct (aliases dead staging bufs)
        f16* ct = (f16*)sm;
        const float* lbp = Lt + (size_t)b * 2048 + mt * 128 + wm;
#pragma unroll
        for (int i = 0; i < 4; ++i) {
            floatx4 lv = *reinterpret_cast<const floatx4*>(lbp + i * 16 + quad * 4);
            floatx4 inv;
#pragma unroll
            for (int r = 0; r < 4; ++r) {
                int rowg = mt * 128 + wm + i * 16 + quad * 4 + r;
                inv[r] = (rowg > 0) ? 1.f / lv[r] : 0.f;
            }
#pragma unroll
            for (int j = 0; j < 4; ++j)
#pragma unroll
                for (int r = 0; r < 4; ++r)
                    ct[(wm + i * 16 + quad * 4 + r) * 136 + wn + j * 16 + l15] =
                        (f16)(acc[i][j][r] * inv[r]);
        }
        __syncthreads();
#pragma unroll
        for (int it = 0; it < 8; ++it) {
            int c = it * 256 + tid, r = c >> 4, c8 = (c & 15) << 3;
            *reinterpret_cast<half8*>(comb + ((size_t)b * 2048 + mt * 128 + r) * 1024 + nb * 128 + c8) =
                *reinterpret_cast<half8*>(ct + r * 136 + c8);
        }
        __syncthreads();   // ct reads done before next tile re-stages over it
    }
}

// ---------------------------------------------------------------------------
// Kernel 5: out = comb @ W_out^T (fp16 gl_lds GEMM, fp32 out). K=1024.
// 1D grid 1024, XCD swizzle. Double-buffered 1-barrier K-loop.
// NT full-line output stores (out never re-read on device).
// ---------------------------------------------------------------------------
__global__ __launch_bounds__(256) void k_out(const f16* __restrict__ comb,
                                             const f16* __restrict__ Wo16,
                                             float* __restrict__ out)
{
    __shared__ char sm[65536];
    const int tid = threadIdx.x, lane = tid & 63, w = tid >> 6;
    const int l15 = lane & 15, quad = lane >> 4;
    const int id = blockIdx.x, xcd = id & 7, u = id >> 3;
    const int mbase = (xcd * 32 + (u >> 2)) * 128;
    const int nbase = (u & 3) * 128;
    const int wm = (w & 1) * 64, wn = (w >> 1) * 64;
    const int ia = wm >> 4, jb = wn >> 4;

    floatx4 acc[4][4];
#pragma unroll
    for (int i = 0; i < 4; ++i)
#pragma unroll
        for (int j = 0; j < 4; ++j) acc[i][j] = (floatx4)0.f;

    auto STAGE = [&](int k0, int bsel) {
        f16* At = (f16*)(sm + bsel * 32768);
        f16* Bt = At + 8192;
#pragma unroll
        for (int jr = 0; jr < 4; ++jr) {
            int bi = jr * 4 + w, i2 = bi >> 1, s = bi & 1;
            gload16(comb + (size_t)(mbase + i2 * 16 + l15) * 1024 + k0 + s * 32 + quad * 8,
                    At + bi * 512);
            gload16(Wo16 + (size_t)(nbase + i2 * 16 + l15) * 1024 + k0 + s * 32 + quad * 8,
                    Bt + bi * 512);
        }
    };

    STAGE(0, 0);
    __syncthreads();
    for (int it = 0; it < 16; ++it) {
        const int cur = it & 1;
        if (it < 15) STAGE((it + 1) * 64, cur ^ 1);
        f16* At = (f16*)(sm + cur * 32768);
        f16* Bt = At + 8192;
#pragma unroll
        for (int s = 0; s < 2; ++s) {
            half8 a[4], bf[4];
#pragma unroll
            for (int i = 0; i < 4; ++i)
                a[i] = *reinterpret_cast<half8*>(At + ((ia + i) * 2 + s) * 512 + lane * 8);
#pragma unroll
            for (int j = 0; j < 4; ++j)
                bf[j] = *reinterpret_cast<half8*>(Bt + ((jb + j) * 2 + s) * 512 + lane * 8);
#pragma unroll
            for (int i = 0; i < 4; ++i)
#pragma unroll
                for (int j = 0; j < 4; ++j)
                    acc[i][j] = MFMA16(a[i], bf[j], acc[i][j]);
        }
        __syncthreads();
    }
    float* cf = (float*)sm;   // [64][132] fp32 padded
    for (int pass = 0; pass < 2; ++pass) {
        __syncthreads();
        if ((w & 1) == pass) {
#pragma unroll
            for (int i = 0; i < 4; ++i)
#pragma unroll
                for (int j = 0; j < 4; ++j)
#pragma unroll
                    for (int r = 0; r < 4; ++r)
                        cf[(i * 16 + quad * 4 + r) * 132 + wn + j * 16 + l15] = acc[i][j][r];
        }
        __syncthreads();
#pragma unroll
        for (int it = 0; it < 8; ++it) {
            int c = it * 256 + tid, row = c >> 5, c4 = (c & 31) << 2;
            __builtin_nontemporal_store(
                *reinterpret_cast<floatx4*>(cf + row * 132 + c4),
                reinterpret_cast<floatx4*>(out + (size_t)(mbase + pass * 64 + row) * 512 + nbase + c4));
        }
    }
}

extern "C" void kernel_launch(void* const* d_in, const int* in_sizes, int n_in,
                              void* d_out, int out_size, void* d_ws, size_t ws_size,
                              hipStream_t stream)
{
    const float* query = (const float*)d_in[0];
    const float* W_in  = (const float*)d_in[1];
    const float* W_out = (const float*)d_in[2];
    float* out = (float*)d_out;

    // ws layout (bytes):
    //   comb fp16 [32768][1024] (mix|q)        @ 0           (67,108,864)
    //   qT   fp16 [16][512][2048]              @ 67,108,864  (33,554,432)
    //   W16  fp16 [Wi 262144 | Wo 524288]      @ 100,663,296 (1,572,864)
    //   X    @ 102,236,160:
    //     q16 fp16 [16*2048*512] (33,554,432)  -- dead after k_qin
    //     Pd  fp16 [16][136][128][128]         @ XOFF        (71,303,168) aliases q16
    //     Rt  f32  [16][16][2048]              @ +71,303,168 (2,097,152)
    //     Lt  f32  [16][2048]                  @ +73,400,320 (131,072)
    //   total XOFF + 73.5MB = 175.8MB (prior ng=16 path proved ws >= 245MB)
    const size_t XOFF = 102236160ull;
    f16* comb = (f16*)d_ws;
    f16* qT   = comb + (size_t)32768 * 1024;
    f16* W16  = qT + (size_t)16 * 512 * 2048;
    f16* q16  = (f16*)((char*)d_ws + XOFF);
    f16* Pd   = (f16*)((char*)d_ws + XOFF);
    float* Rt = (float*)((char*)d_ws + XOFF + 71303168ull);
    float* Lt = (float*)((char*)d_ws + XOFF + 73400320ull);

    k_cvt<<<17152, 256, 0, stream>>>(query, W_in, W_out, q16, W16);
    k_qin<<<1024, 256, 0, stream>>>(q16, W16, comb, qT);
    k_sgemmsm<<<512, 256, 0, stream>>>(comb, Pd, Rt, Lt);
    k_pv<<<512, 256, 0, stream>>>(Pd, qT, comb, Rt, Lt);
    k_out<<<1024, 256, 0, stream>>>(comb, W16 + 262144, out);
}

// Round 8
// 453.616 us; speedup vs baseline: 1.1943x; 1.1943x over previous
//
#include <hip/hip_runtime.h>

typedef _Float16 f16;
typedef _Float16 half8 __attribute__((ext_vector_type(8)));
typedef _Float16 half4 __attribute__((ext_vector_type(4)));
typedef float floatx4 __attribute__((ext_vector_type(4)));
typedef unsigned int uintx4 __attribute__((ext_vector_type(4)));

#define MFMA16(a, b, c) __builtin_amdgcn_mfma_f32_16x16x32_f16(a, b, c, 0, 0, 0)

// async global->LDS, 16B per lane; LDS side = wave-uniform base + lane*16
__device__ __forceinline__ void gload16(const void* g, void* l) {
    __builtin_amdgcn_global_load_lds((const __attribute__((address_space(1))) void*)g,
                                     (__attribute__((address_space(3))) void*)l, 16, 0, 0);
}

// ---------------------------------------------------------------------------
// Kernel 0: convert query [16.8M], W_in [262144], W_out [524288] fp32 -> fp16
// ---------------------------------------------------------------------------
__global__ __launch_bounds__(256) void k_cvt(const float* __restrict__ query,
                                             const float* __restrict__ Wi,
                                             const float* __restrict__ Wo,
                                             f16* __restrict__ q16,
                                             f16* __restrict__ W16)
{
    int i = blockIdx.x * 256 + threadIdx.x;   // float4 index, 4390912 total
    const float4* src;
    f16* dst;
    if (i < 4194304) { src = (const float4*)query + i; dst = q16 + (size_t)i * 4; }
    else if (i < 4259840) { int j = i - 4194304; src = (const float4*)Wi + j; dst = W16 + (size_t)j * 4; }
    else { int j = i - 4259840; src = (const float4*)Wo + j; dst = W16 + 262144 + (size_t)j * 4; }
    float4 v = *src;
    half4 h = {(f16)v.x, (f16)v.y, (f16)v.z, (f16)v.w};
    *reinterpret_cast<half4*>(dst) = h;
}

// ---------------------------------------------------------------------------
// Kernel 1: q = q16 @ W16^T (fp16 gl_lds GEMM, BK=64, 128x128 tile).
// 1D grid 1024 with XCD swizzle. Double-buffered 1-barrier K-loop.
// ---------------------------------------------------------------------------
__global__ __launch_bounds__(256) void k_qin(const f16* __restrict__ q16,
                                             const f16* __restrict__ W16,
                                             f16* __restrict__ comb,
                                             f16* __restrict__ qT)
{
    __shared__ char sm[65536];
    const int tid = threadIdx.x, lane = tid & 63, w = tid >> 6;
    const int l15 = lane & 15, quad = lane >> 4;
    const int id = blockIdx.x, xcd = id & 7, u = id >> 3;
    const int mbase = (xcd * 32 + (u >> 2)) * 128;   // m-tile 0..255
    const int nbase = (u & 3) * 128;                 // n-tile 0..3
    const int wm = (w & 1) * 64, wn = (w >> 1) * 64;
    const int ia = wm >> 4, jb = wn >> 4;

    floatx4 acc[4][4];
#pragma unroll
    for (int i = 0; i < 4; ++i)
#pragma unroll
        for (int j = 0; j < 4; ++j) acc[i][j] = (floatx4)0.f;

    auto STAGE = [&](int k0, int bsel) {
        f16* At = (f16*)(sm + bsel * 32768);
        f16* Bt = At + 8192;
#pragma unroll
        for (int jr = 0; jr < 4; ++jr) {
            int bi = jr * 4 + w, i2 = bi >> 1, s = bi & 1;
            gload16(q16 + (size_t)(mbase + i2 * 16 + l15) * 512 + k0 + s * 32 + quad * 8, At + bi * 512);
            gload16(W16 + (size_t)(nbase + i2 * 16 + l15) * 512 + k0 + s * 32 + quad * 8, Bt + bi * 512);
        }
    };

    STAGE(0, 0);
    __syncthreads();   // buf0 ready
    for (int it = 0; it < 8; ++it) {
        const int cur = it & 1;
        if (it < 7) STAGE((it + 1) * 64, cur ^ 1);   // prefetch overlaps MFMAs
        f16* At = (f16*)(sm + cur * 32768);
        f16* Bt = At + 8192;
#pragma unroll
        for (int s = 0; s < 2; ++s) {
            half8 a[4], bf[4];
#pragma unroll
            for (int i = 0; i < 4; ++i)
                a[i] = *reinterpret_cast<half8*>(At + ((ia + i) * 2 + s) * 512 + lane * 8);
#pragma unroll
            for (int j = 0; j < 4; ++j)
                bf[j] = *reinterpret_cast<half8*>(Bt + ((jb + j) * 2 + s) * 512 + lane * 8);
#pragma unroll
            for (int i = 0; i < 4; ++i)
#pragma unroll
                for (int j = 0; j < 4; ++j)
                    acc[i][j] = MFMA16(a[i], bf[j], acc[i][j]);
        }
        __syncthreads();   // prefetch drained + all waves done with cur
    }
    const int bb = mbase >> 11, tb = mbase & 2047;
    f16* ct = (f16*)sm;   // phase A: row-major [128][136] (aliases dead staging bufs)
#pragma unroll
    for (int i = 0; i < 4; ++i)
#pragma unroll
        for (int j = 0; j < 4; ++j)
#pragma unroll
            for (int r = 0; r < 4; ++r)
                ct[(wm + i * 16 + quad * 4 + r) * 136 + wn + j * 16 + l15] = (f16)acc[i][j][r];
    __syncthreads();
#pragma unroll
    for (int it = 0; it < 8; ++it) {
        int c = it * 256 + tid, r = c >> 4, c8 = (c & 15) << 3;
        *reinterpret_cast<half8*>(comb + (size_t)(mbase + r) * 1024 + 512 + nbase + c8) =
            *reinterpret_cast<half8*>(ct + r * 136 + c8);
    }
    __syncthreads();
    // phase B: column-major [128 cols][136] — vectorized half4 dumps from acc
#pragma unroll
    for (int i = 0; i < 4; ++i)
#pragma unroll
        for (int j = 0; j < 4; ++j) {
            half4 h = {(f16)acc[i][j][0], (f16)acc[i][j][1], (f16)acc[i][j][2], (f16)acc[i][j][3]};
            *reinterpret_cast<half4*>(ct + (wn + j * 16 + l15) * 136 + wm + i * 16 + quad * 4) = h;
        }
    __syncthreads();
    // qT writes: 16 lanes share a d-row -> 256 B contiguous global segments
#pragma unroll
    for (int it = 0; it < 8; ++it) {
        int c = it * 256 + tid, dd = c >> 4, tc = (c & 15) << 3;
        *reinterpret_cast<half8*>(qT + ((size_t)bb * 512 + nbase + dd) * 2048 + tb + tc) =
            *reinterpret_cast<half8*>(ct + dd * 136 + tc);
    }
}

// ---------------------------------------------------------------------------
// Kernel 2: fused S-tile GEMM + PER-TILE softmax (parallel flash).
// One block per (b, causal tile): exactly r4-k_sgemm's high-occupancy
// structure (grid (16,136), uniform work, dbuf 1-barrier pipeline) + a
// register epilogue: tile-local row max m_t (causal-masked), P_t =
// exp(S_t - m_t) fp16 NT-stored, row sums l_t. No cross-tile chain —
// stats compose later (k_stats). S never touches HBM.
// ---------------------------------------------------------------------------
__global__ __launch_bounds__(256) void k_sgemmsm(const f16* __restrict__ comb,
                                                 f16* __restrict__ Pd,
                                                 float* __restrict__ Mt,
                                                 float* __restrict__ Lt)
{
    __shared__ char sm[65536];
    const int tid = threadIdx.x, lane = tid & 63, w = tid >> 6;
    const int l15 = lane & 15, quad = lane >> 4;
    const int wm = (w & 1) * 64, wn = (w >> 1) * 64;
    const int ia = wm >> 4, jb = wn >> 4;

    int bx = blockIdx.y, mt = 0;
    while ((mt + 1) * (mt + 2) / 2 <= bx) ++mt;
    const int nt = bx - mt * (mt + 1) / 2;
    const int b = blockIdx.x;   // grid (16,136): id&7 = b&7 -> batch/XCD pin
    const f16* qa = comb + ((size_t)b * 2048 + mt * 128) * 1024 + 512;
    const f16* qb = comb + ((size_t)b * 2048 + nt * 128) * 1024 + 512;

    floatx4 acc[4][4];
#pragma unroll
    for (int i = 0; i < 4; ++i)
#pragma unroll
        for (int j = 0; j < 4; ++j) acc[i][j] = (floatx4)0.f;

    auto STAGE = [&](int k0, int bsel) {
        f16* At = (f16*)(sm + bsel * 32768);
        f16* Bt = At + 8192;
#pragma unroll
        for (int jr = 0; jr < 4; ++jr) {
            int bi = jr * 4 + w, i2 = bi >> 1, s = bi & 1;
            gload16(qa + (size_t)(i2 * 16 + l15) * 1024 + k0 + s * 32 + quad * 8, At + bi * 512);
            gload16(qb + (size_t)(i2 * 16 + l15) * 1024 + k0 + s * 32 + quad * 8, Bt + bi * 512);
        }
    };

    STAGE(0, 0);
    __syncthreads();
    for (int it = 0; it < 8; ++it) {
        const int cur = it & 1;
        if (it < 7) STAGE((it + 1) * 64, cur ^ 1);
        f16* At = (f16*)(sm + cur * 32768);
        f16* Bt = At + 8192;
#pragma unroll
        for (int s = 0; s < 2; ++s) {
            half8 a[4], bf[4];
#pragma unroll
            for (int i = 0; i < 4; ++i)
                a[i] = *reinterpret_cast<half8*>(At + ((ia + i) * 2 + s) * 512 + lane * 8);
#pragma unroll
            for (int j = 0; j < 4; ++j)
                bf[j] = *reinterpret_cast<half8*>(Bt + ((jb + j) * 2 + s) * 512 + lane * 8);
#pragma unroll
            for (int i = 0; i < 4; ++i)
#pragma unroll
                for (int j = 0; j < 4; ++j)
                    acc[i][j] = MFMA16(a[i], bf[j], acc[i][j]);
        }
        __syncthreads();
    }

    // ---- per-tile softmax epilogue ----
    const bool diag = (nt == mt);
    f16* ct = (f16*)sm;                   // [128][136], aliases dead staging
    float* redm = (float*)(sm + 40960);   // [4 waves][64 rows] partial max
    float* reds = (float*)(sm + 43008);   // [4 waves][64 rows] partial sum
    const int hb = w & 1;

    // masked wave-partial row max (reduce over j regs + l15 lanes)
    float wmax[4][4];
#pragma unroll
    for (int i = 0; i < 4; ++i)
#pragma unroll
        for (int r = 0; r < 4; ++r) {
            const int rowl = wm + i * 16 + quad * 4 + r;
            float mm = -1e38f;
#pragma unroll
            for (int j = 0; j < 4; ++j) {
                float v = acc[i][j][r];
                if (diag && (wn + j * 16 + l15) >= rowl) v = -1e38f;
                mm = fmaxf(mm, v);
            }
            mm = fmaxf(mm, __shfl_xor(mm, 1));
            mm = fmaxf(mm, __shfl_xor(mm, 2));
            mm = fmaxf(mm, __shfl_xor(mm, 4));
            mm = fmaxf(mm, __shfl_xor(mm, 8));
            wmax[i][r] = mm;
        }
    if (l15 == 0)
#pragma unroll
        for (int i = 0; i < 4; ++i)
#pragma unroll
            for (int r = 0; r < 4; ++r)
                redm[w * 64 + i * 16 + quad * 4 + r] = wmax[i][r];
    __syncthreads();

    // exp + P->ct + row partial sums
#pragma unroll
    for (int i = 0; i < 4; ++i)
#pragma unroll
        for (int r = 0; r < 4; ++r) {
            const int idx = i * 16 + quad * 4 + r;
            const int rowl = wm + idx;
            const float m = fmaxf(redm[hb * 64 + idx], redm[(hb + 2) * 64 + idx]);
            float ssum = 0.f;
#pragma unroll
            for (int j = 0; j < 4; ++j) {
                const int col = wn + j * 16 + l15;
                const bool valid = !diag || (col < rowl);
                float e = valid ? __expf(acc[i][j][r] - m) : 0.f;
                ssum += e;
                ct[rowl * 136 + col] = (f16)e;
            }
            ssum += __shfl_xor(ssum, 1);
            ssum += __shfl_xor(ssum, 2);
            ssum += __shfl_xor(ssum, 4);
            ssum += __shfl_xor(ssum, 8);
            wmax[i][r] = ssum;   // reuse as sum stash
        }
    if (l15 == 0)
#pragma unroll
        for (int i = 0; i < 4; ++i)
#pragma unroll
            for (int r = 0; r < 4; ++r)
                reds[w * 64 + i * 16 + quad * 4 + r] = wmax[i][r];
    __syncthreads();

    // m/l tables: one thread per row, contiguous 512B stores
    if (tid < 128) {
        const int h2 = tid >> 6, i2 = tid & 63;
        const float mm = fmaxf(redm[h2 * 64 + i2], redm[(h2 + 2) * 64 + i2]);
        const float ll = reds[h2 * 64 + i2] + reds[(h2 + 2) * 64 + i2];
        const size_t o = (((size_t)b * 16 + nt) << 11) + mt * 128 + tid;
        Mt[o] = mm;
        Lt[o] = ll;
    }
    // P' tile -> dense fp16 [b][tile][128][128], non-temporal (read once by k_pv)
    f16* Pt = Pd + ((size_t)(b * 136 + bx) << 14);
#pragma unroll
    for (int itp = 0; itp < 8; ++itp) {
        int c = itp * 256 + tid, r_ = c >> 4, c8 = (c & 15) << 3;
        __builtin_nontemporal_store(
            *reinterpret_cast<uintx4*>(ct + r_ * 136 + c8),
            reinterpret_cast<uintx4*>(Pt + r_ * 128 + c8));
    }
}

// ---------------------------------------------------------------------------
// Kernel 3: combine per-tile stats -> per-tile scale factors, IN PLACE:
// F[b][t][row] = exp(m_t - M) / l  (0 if l==0, i.e. global row 0).
// M = max_t m_t, l = sum_t l_t * exp(m_t - M). One thread per row.
// ---------------------------------------------------------------------------
__global__ __launch_bounds__(256) void k_stats(float* Mt, const float* __restrict__ Lt)
{
    const int b = blockIdx.x, row = blockIdx.y * 256 + threadIdx.x;
    const int mtr = row >> 7;
    float mv[16], lv[16];
    for (int t = 0; t <= mtr; ++t) {
        const size_t o = (((size_t)b * 16 + t) << 11) + row;
        mv[t] = Mt[o];
        lv[t] = Lt[o];
    }
    float M = -1e38f;
    for (int t = 0; t <= mtr; ++t) M = fmaxf(M, mv[t]);
    float l = 0.f;
    for (int t = 0; t <= mtr; ++t) l += lv[t] * __expf(mv[t] - M);
    const float invl = (l > 0.f) ? 1.f / l : 0.f;
    for (int t = 0; t <= mtr; ++t)
        Mt[(((size_t)b * 16 + t) << 11) + row] = __expf(mv[t] - M) * invl;
}

// ---------------------------------------------------------------------------
// Kernel 4: mix = sum_t F_t * (P_t @ qT_t). Two accumulators: acc collects
// one tile's MFMAs; on tile completion accT += acc * F_t (row-scale commutes
// with matmul), acc reset. Normalization folded into F -> plain epilogue.
// Uniform-work pairing (mt=p with 15-p) + dbuf 1-barrier pipeline.
// ---------------------------------------------------------------------------
__global__ __launch_bounds__(256) void k_pv(const f16* __restrict__ Pd,
                                            const f16* __restrict__ qT,
                                            f16* __restrict__ comb,
                                            const float* __restrict__ Ft)
{
    __shared__ char sm[65536];
    const int tid = threadIdx.x, lane = tid & 63, w = tid >> 6;
    const int l15 = lane & 15, quad = lane >> 4;
    const int wm = (w & 1) * 64, wn = (w >> 1) * 64;
    const int ia = wm >> 4, jb = wn >> 4;
    const int id = blockIdx.x;
    const int p = id & 7, nb = (id >> 3) & 3, b = id >> 5;
    const f16* Pdb = Pd + ((size_t)b * 136 << 14);
    const f16* qTb = qT + ((size_t)b * 512 + nb * 128) * 2048;

    for (int t = 0; t < 2; ++t) {
        const int mt = t ? (15 - p) : p;
        const int tb0 = mt * (mt + 1) / 2;
        const int kit = (mt + 1) * 2;

        floatx4 acc[4][4], accT[4][4];
#pragma unroll
        for (int i = 0; i < 4; ++i)
#pragma unroll
            for (int j = 0; j < 4; ++j) { acc[i][j] = (floatx4)0.f; accT[i][j] = (floatx4)0.f; }

        auto STAGE = [&](int it, int bsel) {
            f16* At = (f16*)(sm + bsel * 32768);
            f16* Bt = At + 8192;
            const int k0 = it * 64;
#pragma unroll
            for (int jr = 0; jr < 4; ++jr) {
                int bi = jr * 4 + w, i2 = bi >> 1, s = bi & 1;
                gload16(Pdb + ((size_t)(tb0 + (k0 >> 7)) << 14) + (size_t)(i2 * 16 + l15) * 128
                            + (k0 & 64) + s * 32 + quad * 8,
                        At + bi * 512);
                gload16(qTb + (size_t)(i2 * 16 + l15) * 2048 + k0 + s * 32 + quad * 8, Bt + bi * 512);
            }
        };

        STAGE(0, 0);
        __syncthreads();   // buf0 ready
        for (int it = 0; it < kit; ++it) {
            const int cur = it & 1;
            if (it + 1 < kit) STAGE(it + 1, cur ^ 1);   // prefetch overlaps compute
            f16* At = (f16*)(sm + cur * 32768);
            f16* Bt = At + 8192;
#pragma unroll
            for (int s = 0; s < 2; ++s) {
                half8 a[4], bf[4];
#pragma unroll
                for (int i = 0; i < 4; ++i)
                    a[i] = *reinterpret_cast<half8*>(At + ((ia + i) * 2 + s) * 512 + lane * 8);
#pragma unroll
                for (int j = 0; j < 4; ++j)
                    bf[j] = *reinterpret_cast<half8*>(Bt + ((jb + j) * 2 + s) * 512 + lane * 8);
#pragma unroll
                for (int i = 0; i < 4; ++i)
#pragma unroll
                    for (int j = 0; j < 4; ++j)
                        acc[i][j] = MFMA16(a[i], bf[j], acc[i][j]);
            }
            if (it & 1) {   // tile (it>>1) complete: fold with its F, reset
                const int tt = it >> 1;
                const float* fp = Ft + (((size_t)b * 16 + tt) << 11) + mt * 128 + wm;
#pragma unroll
                for (int i = 0; i < 4; ++i) {
                    floatx4 fv = *reinterpret_cast<const floatx4*>(fp + i * 16 + quad * 4);
#pragma unroll
                    for (int j = 0; j < 4; ++j) {
                        accT[i][j] += acc[i][j] * fv;
                        acc[i][j] = (floatx4)0.f;
                    }
                }
            }
            __syncthreads();
        }

        // epilogue: bounce via ct (aliases dead staging bufs), store comb
        f16* ct = (f16*)sm;
#pragma unroll
        for (int i = 0; i < 4; ++i)
#pragma unroll
            for (int j = 0; j < 4; ++j)
#pragma unroll
                for (int r = 0; r < 4; ++r)
                    ct[(wm + i * 16 + quad * 4 + r) * 136 + wn + j * 16 + l15] = (f16)accT[i][j][r];
        __syncthreads();
#pragma unroll
        for (int it = 0; it < 8; ++it) {
            int c = it * 256 + tid, r = c >> 4, c8 = (c & 15) << 3;
            *reinterpret_cast<half8*>(comb + ((size_t)b * 2048 + mt * 128 + r) * 1024 + nb * 128 + c8) =
                *reinterpret_cast<half8*>(ct + r * 136 + c8);
        }
        __syncthreads();   // ct reads done before next tile re-stages over it
    }
}

// ---------------------------------------------------------------------------
// Kernel 5: out = comb @ W_out^T (fp16 gl_lds GEMM, fp32 out). K=1024.
// 1D grid 1024, XCD swizzle. Double-buffered 1-barrier K-loop.
// NT full-line output stores (out never re-read on device).
// ---------------------------------------------------------------------------
__global__ __launch_bounds__(256) void k_out(const f16* __restrict__ comb,
                                             const f16* __restrict__ Wo16,
                                             float* __restrict__ out)
{
    __shared__ char sm[65536];
    const int tid = threadIdx.x, lane = tid & 63, w = tid >> 6;
    const int l15 = lane & 15, quad = lane >> 4;
    const int id = blockIdx.x, xcd = id & 7, u = id >> 3;
    const int mbase = (xcd * 32 + (u >> 2)) * 128;
    const int nbase = (u & 3) * 128;
    const int wm = (w & 1) * 64, wn = (w >> 1) * 64;
    const int ia = wm >> 4, jb = wn >> 4;

    floatx4 acc[4][4];
#pragma unroll
    for (int i = 0; i < 4; ++i)
#pragma unroll
        for (int j = 0; j < 4; ++j) acc[i][j] = (floatx4)0.f;

    auto STAGE = [&](int k0, int bsel) {
        f16* At = (f16*)(sm + bsel * 32768);
        f16* Bt = At + 8192;
#pragma unroll
        for (int jr = 0; jr < 4; ++jr) {
            int bi = jr * 4 + w, i2 = bi >> 1, s = bi & 1;
            gload16(comb + (size_t)(mbase + i2 * 16 + l15) * 1024 + k0 + s * 32 + quad * 8,
                    At + bi * 512);
            gload16(Wo16 + (size_t)(nbase + i2 * 16 + l15) * 1024 + k0 + s * 32 + quad * 8,
                    Bt + bi * 512);
        }
    };

    STAGE(0, 0);
    __syncthreads();
    for (int it = 0; it < 16; ++it) {
        const int cur = it & 1;
        if (it < 15) STAGE((it + 1) * 64, cur ^ 1);
        f16* At = (f16*)(sm + cur * 32768);
        f16* Bt = At + 8192;
#pragma unroll
        for (int s = 0; s < 2; ++s) {
            half8 a[4], bf[4];
#pragma unroll
            for (int i = 0; i < 4; ++i)
                a[i] = *reinterpret_cast<half8*>(At + ((ia + i) * 2 + s) * 512 + lane * 8);
#pragma unroll
            for (int j = 0; j < 4; ++j)
                bf[j] = *reinterpret_cast<half8*>(Bt + ((jb + j) * 2 + s) * 512 + lane * 8);
#pragma unroll
            for (int i = 0; i < 4; ++i)
#pragma unroll
                for (int j = 0; j < 4; ++j)
                    acc[i][j] = MFMA16(a[i], bf[j], acc[i][j]);
        }
        __syncthreads();
    }
    float* cf = (float*)sm;   // [64][132] fp32 padded
    for (int pass = 0; pass < 2; ++pass) {
        __syncthreads();
        if ((w & 1) == pass) {
#pragma unroll
            for (int i = 0; i < 4; ++i)
#pragma unroll
                for (int j = 0; j < 4; ++j)
#pragma unroll
                    for (int r = 0; r < 4; ++r)
                        cf[(i * 16 + quad * 4 + r) * 132 + wn + j * 16 + l15] = acc[i][j][r];
        }
        __syncthreads();
#pragma unroll
        for (int it = 0; it < 8; ++it) {
            int c = it * 256 + tid, row = c >> 5, c4 = (c & 31) << 2;
            __builtin_nontemporal_store(
                *reinterpret_cast<floatx4*>(cf + row * 132 + c4),
                reinterpret_cast<floatx4*>(out + (size_t)(mbase + pass * 64 + row) * 512 + nbase + c4));
        }
    }
}

extern "C" void kernel_launch(void* const* d_in, const int* in_sizes, int n_in,
                              void* d_out, int out_size, void* d_ws, size_t ws_size,
                              hipStream_t stream)
{
    const float* query = (const float*)d_in[0];
    const float* W_in  = (const float*)d_in[1];
    const float* W_out = (const float*)d_in[2];
    float* out = (float*)d_out;

    // ws layout (bytes):
    //   comb fp16 [32768][1024] (mix|q)        @ 0           (67,108,864)
    //   qT   fp16 [16][512][2048]              @ 67,108,864  (33,554,432)
    //   W16  fp16 [Wi 262144 | Wo 524288]      @ 100,663,296 (1,572,864)
    //   X    @ 102,236,160:
    //     q16 fp16 [16*2048*512] (33,554,432)  -- dead after k_qin
    //     Pd  fp16 [16][136][128][128]         @ XOFF        (71,303,168) aliases q16
    //     Mt  f32  [16][16][2048] (m_t -> F_t) @ +71,303,168 (2,097,152)
    //     Lt  f32  [16][16][2048] (l_t)        @ +73,400,320 (2,097,152)
    //   total = XOFF + 75.5MB = 177.7MB (ws proved >= 245MB in earlier rounds)
    const size_t XOFF = 102236160ull;
    f16* comb = (f16*)d_ws;
    f16* qT   = comb + (size_t)32768 * 1024;
    f16* W16  = qT + (size_t)16 * 512 * 2048;
    f16* q16  = (f16*)((char*)d_ws + XOFF);
    f16* Pd   = (f16*)((char*)d_ws + XOFF);
    float* Mt = (float*)((char*)d_ws + XOFF + 71303168ull);
    float* Lt = (float*)((char*)d_ws + XOFF + 73400320ull);

    k_cvt<<<17152, 256, 0, stream>>>(query, W_in, W_out, q16, W16);
    k_qin<<<1024, 256, 0, stream>>>(q16, W16, comb, qT);
    k_sgemmsm<<<dim3(16, 136), 256, 0, stream>>>(comb, Pd, Mt, Lt);
    k_stats<<<dim3(16, 8), 256, 0, stream>>>(Mt, Lt);
    k_pv<<<512, 256, 0, stream>>>(Pd, qT, comb, Mt);
    k_out<<<1024, 256, 0, stream>>>(comb, W16 + 262144, out);
}

// Round 9
// 429.355 us; speedup vs baseline: 1.2618x; 1.0565x over previous
//
#include <hip/hip_runtime.h>

typedef _Float16 f16;
typedef _Float16 half8 __attribute__((ext_vector_type(8)));
typedef _Float16 half4 __attribute__((ext_vector_type(4)));
typedef float floatx4 __attribute__((ext_vector_type(4)));
typedef unsigned int uintx4 __attribute__((ext_vector_type(4)));

#define MFMA16(a, b, c) __builtin_amdgcn_mfma_f32_16x16x32_f16(a, b, c, 0, 0, 0)

// async global->LDS, 16B per lane; LDS side = wave-uniform base + lane*16
__device__ __forceinline__ void gload16(const void* g, void* l) {
    __builtin_amdgcn_global_load_lds((const __attribute__((address_space(1))) void*)g,
                                     (__attribute__((address_space(3))) void*)l, 16, 0, 0);
}

// ---------------------------------------------------------------------------
// Kernel 0: convert query [16.8M], W_in [262144], W_out [524288] fp32 -> fp16
// ---------------------------------------------------------------------------
__global__ __launch_bounds__(256) void k_cvt(const float* __restrict__ query,
                                             const float* __restrict__ Wi,
                                             const float* __restrict__ Wo,
                                             f16* __restrict__ q16,
                                             f16* __restrict__ W16)
{
    int i = blockIdx.x * 256 + threadIdx.x;   // float4 index, 4390912 total
    const float4* src;
    f16* dst;
    if (i < 4194304) { src = (const float4*)query + i; dst = q16 + (size_t)i * 4; }
    else if (i < 4259840) { int j = i - 4194304; src = (const float4*)Wi + j; dst = W16 + (size_t)j * 4; }
    else { int j = i - 4259840; src = (const float4*)Wo + j; dst = W16 + 262144 + (size_t)j * 4; }
    float4 v = *src;
    half4 h = {(f16)v.x, (f16)v.y, (f16)v.z, (f16)v.w};
    *reinterpret_cast<half4*>(dst) = h;
}

// ---------------------------------------------------------------------------
// Kernel 1: q = q16 @ W16^T (fp16 gl_lds GEMM, BK=64, 128x128 tile).
// 1D grid 1024 with XCD swizzle. Double-buffered 1-barrier K-loop.
// ---------------------------------------------------------------------------
__global__ __launch_bounds__(256) void k_qin(const f16* __restrict__ q16,
                                             const f16* __restrict__ W16,
                                             f16* __restrict__ comb,
                                             f16* __restrict__ qT)
{
    __shared__ char sm[65536];
    const int tid = threadIdx.x, lane = tid & 63, w = tid >> 6;
    const int l15 = lane & 15, quad = lane >> 4;
    const int id = blockIdx.x, xcd = id & 7, u = id >> 3;
    const int mbase = (xcd * 32 + (u >> 2)) * 128;   // m-tile 0..255
    const int nbase = (u & 3) * 128;                 // n-tile 0..3
    const int wm = (w & 1) * 64, wn = (w >> 1) * 64;
    const int ia = wm >> 4, jb = wn >> 4;

    floatx4 acc[4][4];
#pragma unroll
    for (int i = 0; i < 4; ++i)
#pragma unroll
        for (int j = 0; j < 4; ++j) acc[i][j] = (floatx4)0.f;

    auto STAGE = [&](int k0, int bsel) {
        f16* At = (f16*)(sm + bsel * 32768);
        f16* Bt = At + 8192;
#pragma unroll
        for (int jr = 0; jr < 4; ++jr) {
            int bi = jr * 4 + w, i2 = bi >> 1, s = bi & 1;
            gload16(q16 + (size_t)(mbase + i2 * 16 + l15) * 512 + k0 + s * 32 + quad * 8, At + bi * 512);
            gload16(W16 + (size_t)(nbase + i2 * 16 + l15) * 512 + k0 + s * 32 + quad * 8, Bt + bi * 512);
        }
    };

    STAGE(0, 0);
    __syncthreads();   // buf0 ready
    for (int it = 0; it < 8; ++it) {
        const int cur = it & 1;
        if (it < 7) STAGE((it + 1) * 64, cur ^ 1);   // prefetch overlaps MFMAs
        f16* At = (f16*)(sm + cur * 32768);
        f16* Bt = At + 8192;
#pragma unroll
        for (int s = 0; s < 2; ++s) {
            half8 a[4], bf[4];
#pragma unroll
            for (int i = 0; i < 4; ++i)
                a[i] = *reinterpret_cast<half8*>(At + ((ia + i) * 2 + s) * 512 + lane * 8);
#pragma unroll
            for (int j = 0; j < 4; ++j)
                bf[j] = *reinterpret_cast<half8*>(Bt + ((jb + j) * 2 + s) * 512 + lane * 8);
#pragma unroll
            for (int i = 0; i < 4; ++i)
#pragma unroll
                for (int j = 0; j < 4; ++j)
                    acc[i][j] = MFMA16(a[i], bf[j], acc[i][j]);
        }
        __syncthreads();   // prefetch drained + all waves done with cur
    }
    const int bb = mbase >> 11, tb = mbase & 2047;
    f16* ct = (f16*)sm;   // phase A: row-major [128][136] (aliases dead staging bufs)
#pragma unroll
    for (int i = 0; i < 4; ++i)
#pragma unroll
        for (int j = 0; j < 4; ++j)
#pragma unroll
            for (int r = 0; r < 4; ++r)
                ct[(wm + i * 16 + quad * 4 + r) * 136 + wn + j * 16 + l15] = (f16)acc[i][j][r];
    __syncthreads();
#pragma unroll
    for (int it = 0; it < 8; ++it) {
        int c = it * 256 + tid, r = c >> 4, c8 = (c & 15) << 3;
        *reinterpret_cast<half8*>(comb + (size_t)(mbase + r) * 1024 + 512 + nbase + c8) =
            *reinterpret_cast<half8*>(ct + r * 136 + c8);
    }
    __syncthreads();
    // phase B: column-major [128 cols][136] — vectorized half4 dumps from acc
#pragma unroll
    for (int i = 0; i < 4; ++i)
#pragma unroll
        for (int j = 0; j < 4; ++j) {
            half4 h = {(f16)acc[i][j][0], (f16)acc[i][j][1], (f16)acc[i][j][2], (f16)acc[i][j][3]};
            *reinterpret_cast<half4*>(ct + (wn + j * 16 + l15) * 136 + wm + i * 16 + quad * 4) = h;
        }
    __syncthreads();
    // qT writes: 16 lanes share a d-row -> 256 B contiguous global segments
#pragma unroll
    for (int it = 0; it < 8; ++it) {
        int c = it * 256 + tid, dd = c >> 4, tc = (c & 15) << 3;
        *reinterpret_cast<half8*>(qT + ((size_t)bb * 512 + nbase + dd) * 2048 + tb + tc) =
            *reinterpret_cast<half8*>(ct + dd * 136 + tc);
    }
}

// ---------------------------------------------------------------------------
// Kernel 2: fused S-tile GEMM + PER-TILE softmax (parallel flash).
// One block per (b, causal tile), grid (16,136), dbuf 1-barrier pipeline,
// register epilogue: tile-local row max m_t (causal-masked), P_t =
// exp(S_t - m_t) fp16, row sums l_t. Stats compose later (k_stats).
// S never touches HBM. P' stored with NORMAL (cached) stores — it is
// re-read 4x by k_pv's nb-blocks (r8 lesson: NT here pushed P' out of
// L2/L3 and k_pv paid 170MB of HBM fetch, +50µs).
// ---------------------------------------------------------------------------
__global__ __launch_bounds__(256) void k_sgemmsm(const f16* __restrict__ comb,
                                                 f16* __restrict__ Pd,
                                                 float* __restrict__ Mt,
                                                 float* __restrict__ Lt)
{
    __shared__ char sm[65536];
    const int tid = threadIdx.x, lane = tid & 63, w = tid >> 6;
    const int l15 = lane & 15, quad = lane >> 4;
    const int wm = (w & 1) * 64, wn = (w >> 1) * 64;
    const int ia = wm >> 4, jb = wn >> 4;

    int bx = blockIdx.y, mt = 0;
    while ((mt + 1) * (mt + 2) / 2 <= bx) ++mt;
    const int nt = bx - mt * (mt + 1) / 2;
    const int b = blockIdx.x;   // grid (16,136): id&7 = b&7 -> batch/XCD pin
    const f16* qa = comb + ((size_t)b * 2048 + mt * 128) * 1024 + 512;
    const f16* qb = comb + ((size_t)b * 2048 + nt * 128) * 1024 + 512;

    floatx4 acc[4][4];
#pragma unroll
    for (int i = 0; i < 4; ++i)
#pragma unroll
        for (int j = 0; j < 4; ++j) acc[i][j] = (floatx4)0.f;

    auto STAGE = [&](int k0, int bsel) {
        f16* At = (f16*)(sm + bsel * 32768);
        f16* Bt = At + 8192;
#pragma unroll
        for (int jr = 0; jr < 4; ++jr) {
            int bi = jr * 4 + w, i2 = bi >> 1, s = bi & 1;
            gload16(qa + (size_t)(i2 * 16 + l15) * 1024 + k0 + s * 32 + quad * 8, At + bi * 512);
            gload16(qb + (size_t)(i2 * 16 + l15) * 1024 + k0 + s * 32 + quad * 8, Bt + bi * 512);
        }
    };

    STAGE(0, 0);
    __syncthreads();
    for (int it = 0; it < 8; ++it) {
        const int cur = it & 1;
        if (it < 7) STAGE((it + 1) * 64, cur ^ 1);
        f16* At = (f16*)(sm + cur * 32768);
        f16* Bt = At + 8192;
#pragma unroll
        for (int s = 0; s < 2; ++s) {
            half8 a[4], bf[4];
#pragma unroll
            for (int i = 0; i < 4; ++i)
                a[i] = *reinterpret_cast<half8*>(At + ((ia + i) * 2 + s) * 512 + lane * 8);
#pragma unroll
            for (int j = 0; j < 4; ++j)
                bf[j] = *reinterpret_cast<half8*>(Bt + ((jb + j) * 2 + s) * 512 + lane * 8);
#pragma unroll
            for (int i = 0; i < 4; ++i)
#pragma unroll
                for (int j = 0; j < 4; ++j)
                    acc[i][j] = MFMA16(a[i], bf[j], acc[i][j]);
        }
        __syncthreads();
    }

    // ---- per-tile softmax epilogue ----
    const bool diag = (nt == mt);
    f16* ct = (f16*)sm;                   // [128][136], aliases dead staging
    float* redm = (float*)(sm + 40960);   // [4 waves][64 rows] partial max
    float* reds = (float*)(sm + 43008);   // [4 waves][64 rows] partial sum
    const int hb = w & 1;

    // masked wave-partial row max (reduce over j regs + l15 lanes)
    float wmax[4][4];
#pragma unroll
    for (int i = 0; i < 4; ++i)
#pragma unroll
        for (int r = 0; r < 4; ++r) {
            const int rowl = wm + i * 16 + quad * 4 + r;
            float mm = -1e38f;
#pragma unroll
            for (int j = 0; j < 4; ++j) {
                float v = acc[i][j][r];
                if (diag && (wn + j * 16 + l15) >= rowl) v = -1e38f;
                mm = fmaxf(mm, v);
            }
            mm = fmaxf(mm, __shfl_xor(mm, 1));
            mm = fmaxf(mm, __shfl_xor(mm, 2));
            mm = fmaxf(mm, __shfl_xor(mm, 4));
            mm = fmaxf(mm, __shfl_xor(mm, 8));
            wmax[i][r] = mm;
        }
    if (l15 == 0)
#pragma unroll
        for (int i = 0; i < 4; ++i)
#pragma unroll
            for (int r = 0; r < 4; ++r)
                redm[w * 64 + i * 16 + quad * 4 + r] = wmax[i][r];
    __syncthreads();

    // exp + P->ct + row partial sums
#pragma unroll
    for (int i = 0; i < 4; ++i)
#pragma unroll
        for (int r = 0; r < 4; ++r) {
            const int idx = i * 16 + quad * 4 + r;
            const int rowl = wm + idx;
            const float m = fmaxf(redm[hb * 64 + idx], redm[(hb + 2) * 64 + idx]);
            float ssum = 0.f;
#pragma unroll
            for (int j = 0; j < 4; ++j) {
                const int col = wn + j * 16 + l15;
                const bool valid = !diag || (col < rowl);
                float e = valid ? __expf(acc[i][j][r] - m) : 0.f;
                ssum += e;
                ct[rowl * 136 + col] = (f16)e;
            }
            ssum += __shfl_xor(ssum, 1);
            ssum += __shfl_xor(ssum, 2);
            ssum += __shfl_xor(ssum, 4);
            ssum += __shfl_xor(ssum, 8);
            wmax[i][r] = ssum;   // reuse as sum stash
        }
    if (l15 == 0)
#pragma unroll
        for (int i = 0; i < 4; ++i)
#pragma unroll
            for (int r = 0; r < 4; ++r)
                reds[w * 64 + i * 16 + quad * 4 + r] = wmax[i][r];
    __syncthreads();

    // m/l tables: one thread per row, contiguous 512B stores
    if (tid < 128) {
        const int h2 = tid >> 6, i2 = tid & 63;
        const float mm = fmaxf(redm[h2 * 64 + i2], redm[(h2 + 2) * 64 + i2]);
        const float ll = reds[h2 * 64 + i2] + reds[(h2 + 2) * 64 + i2];
        const size_t o = (((size_t)b * 16 + nt) << 11) + mt * 128 + tid;
        Mt[o] = mm;
        Lt[o] = ll;
    }
    // P' tile -> dense fp16 [b][tile][128][128], NORMAL stores (L2/L3-allocate:
    // k_pv re-reads each tile 4x)
    f16* Pt = Pd + ((size_t)(b * 136 + bx) << 14);
#pragma unroll
    for (int itp = 0; itp < 8; ++itp) {
        int c = itp * 256 + tid, r_ = c >> 4, c8 = (c & 15) << 3;
        *reinterpret_cast<half8*>(Pt + r_ * 128 + c8) =
            *reinterpret_cast<half8*>(ct + r_ * 136 + c8);
    }
}

// ---------------------------------------------------------------------------
// Kernel 3: combine per-tile stats -> per-tile scale factors, IN PLACE:
// F[b][t][row] = exp(m_t - M) / l  (0 if l==0, i.e. global row 0).
// M = max_t m_t, l = sum_t l_t * exp(m_t - M). One thread per row.
// ---------------------------------------------------------------------------
__global__ __launch_bounds__(256) void k_stats(float* Mt, const float* __restrict__ Lt)
{
    const int b = blockIdx.x, row = blockIdx.y * 256 + threadIdx.x;
    const int mtr = row >> 7;
    float mv[16], lv[16];
    for (int t = 0; t <= mtr; ++t) {
        const size_t o = (((size_t)b * 16 + t) << 11) + row;
        mv[t] = Mt[o];
        lv[t] = Lt[o];
    }
    float M = -1e38f;
    for (int t = 0; t <= mtr; ++t) M = fmaxf(M, mv[t]);
    float l = 0.f;
    for (int t = 0; t <= mtr; ++t) l += lv[t] * __expf(mv[t] - M);
    const float invl = (l > 0.f) ? 1.f / l : 0.f;
    for (int t = 0; t <= mtr; ++t)
        Mt[(((size_t)b * 16 + t) << 11) + row] = __expf(mv[t] - M) * invl;
}

// ---------------------------------------------------------------------------
// Kernel 4: mix = sum_t F_t * (P_t @ qT_t). Two accumulators: acc collects
// one tile's MFMAs; on tile completion accT += acc * F_t (row-scale commutes
// with matmul), acc reset. Normalization folded into F -> plain epilogue.
// Uniform-work pairing (mt=p with 15-p) + dbuf 1-barrier pipeline.
// ---------------------------------------------------------------------------
__global__ __launch_bounds__(256) void k_pv(const f16* __restrict__ Pd,
                                            const f16* __restrict__ qT,
                                            f16* __restrict__ comb,
                                            const float* __restrict__ Ft)
{
    __shared__ char sm[65536];
    const int tid = threadIdx.x, lane = tid & 63, w = tid >> 6;
    const int l15 = lane & 15, quad = lane >> 4;
    const int wm = (w & 1) * 64, wn = (w >> 1) * 64;
    const int ia = wm >> 4, jb = wn >> 4;
    const int id = blockIdx.x;
    const int p = id & 7, nb = (id >> 3) & 3, b = id >> 5;
    const f16* Pdb = Pd + ((size_t)b * 136 << 14);
    const f16* qTb = qT + ((size_t)b * 512 + nb * 128) * 2048;

    for (int t = 0; t < 2; ++t) {
        const int mt = t ? (15 - p) : p;
        const int tb0 = mt * (mt + 1) / 2;
        const int kit = (mt + 1) * 2;

        floatx4 acc[4][4], accT[4][4];
#pragma unroll
        for (int i = 0; i < 4; ++i)
#pragma unroll
            for (int j = 0; j < 4; ++j) { acc[i][j] = (floatx4)0.f; accT[i][j] = (floatx4)0.f; }

        auto STAGE = [&](int it, int bsel) {
            f16* At = (f16*)(sm + bsel * 32768);
            f16* Bt = At + 8192;
            const int k0 = it * 64;
#pragma unroll
            for (int jr = 0; jr < 4; ++jr) {
                int bi = jr * 4 + w, i2 = bi >> 1, s = bi & 1;
                gload16(Pdb + ((size_t)(tb0 + (k0 >> 7)) << 14) + (size_t)(i2 * 16 + l15) * 128
                            + (k0 & 64) + s * 32 + quad * 8,
                        At + bi * 512);
                gload16(qTb + (size_t)(i2 * 16 + l15) * 2048 + k0 + s * 32 + quad * 8, Bt + bi * 512);
            }
        };

        STAGE(0, 0);
        __syncthreads();   // buf0 ready
        for (int it = 0; it < kit; ++it) {
            const int cur = it & 1;
            if (it + 1 < kit) STAGE(it + 1, cur ^ 1);   // prefetch overlaps compute
            f16* At = (f16*)(sm + cur * 32768);
            f16* Bt = At + 8192;
#pragma unroll
            for (int s = 0; s < 2; ++s) {
                half8 a[4], bf[4];
#pragma unroll
                for (int i = 0; i < 4; ++i)
                    a[i] = *reinterpret_cast<half8*>(At + ((ia + i) * 2 + s) * 512 + lane * 8);
#pragma unroll
                for (int j = 0; j < 4; ++j)
                    bf[j] = *reinterpret_cast<half8*>(Bt + ((jb + j) * 2 + s) * 512 + lane * 8);
#pragma unroll
                for (int i = 0; i < 4; ++i)
#pragma unroll
                    for (int j = 0; j < 4; ++j)
                        acc[i][j] = MFMA16(a[i], bf[j], acc[i][j]);
            }
            if (it & 1) {   // tile (it>>1) complete: fold with its F, reset
                const int tt = it >> 1;
                const float* fp = Ft + (((size_t)b * 16 + tt) << 11) + mt * 128 + wm;
#pragma unroll
                for (int i = 0; i < 4; ++i) {
                    floatx4 fv = *reinterpret_cast<const floatx4*>(fp + i * 16 + quad * 4);
#pragma unroll
                    for (int j = 0; j < 4; ++j) {
                        accT[i][j] += acc[i][j] * fv;
                        acc[i][j] = (floatx4)0.f;
                    }
                }
            }
            __syncthreads();
        }

        // epilogue: bounce via ct (aliases dead staging bufs), store comb
        f16* ct = (f16*)sm;
#pragma unroll
        for (int i = 0; i < 4; ++i)
#pragma unroll
            for (int j = 0; j < 4; ++j)
#pragma unroll
                for (int r = 0; r < 4; ++r)
                    ct[(wm + i * 16 + quad * 4 + r) * 136 + wn + j * 16 + l15] = (f16)accT[i][j][r];
        __syncthreads();
#pragma unroll
        for (int it = 0; it < 8; ++it) {
            int c = it * 256 + tid, r = c >> 4, c8 = (c & 15) << 3;
            *reinterpret_cast<half8*>(comb + ((size_t)b * 2048 + mt * 128 + r) * 1024 + nb * 128 + c8) =
                *reinterpret_cast<half8*>(ct + r * 136 + c8);
        }
        __syncthreads();   // ct reads done before next tile re-stages over it
    }
}

// ---------------------------------------------------------------------------
// Kernel 5: out = comb @ W_out^T (fp16 gl_lds GEMM, fp32 out). K=1024.
// 1D grid 1024, XCD swizzle. Double-buffered 1-barrier K-loop.
// NT full-line output stores (out never re-read on device -> NT correct here).
// ---------------------------------------------------------------------------
__global__ __launch_bounds__(256) void k_out(const f16* __restrict__ comb,
                                             const f16* __restrict__ Wo16,
                                             float* __restrict__ out)
{
    __shared__ char sm[65536];
    const int tid = threadIdx.x, lane = tid & 63, w = tid >> 6;
    const int l15 = lane & 15, quad = lane >> 4;
    const int id = blockIdx.x, xcd = id & 7, u = id >> 3;
    const int mbase = (xcd * 32 + (u >> 2)) * 128;
    const int nbase = (u & 3) * 128;
    const int wm = (w & 1) * 64, wn = (w >> 1) * 64;
    const int ia = wm >> 4, jb = wn >> 4;

    floatx4 acc[4][4];
#pragma unroll
    for (int i = 0; i < 4; ++i)
#pragma unroll
        for (int j = 0; j < 4; ++j) acc[i][j] = (floatx4)0.f;

    auto STAGE = [&](int k0, int bsel) {
        f16* At = (f16*)(sm + bsel * 32768);
        f16* Bt = At + 8192;
#pragma unroll
        for (int jr = 0; jr < 4; ++jr) {
            int bi = jr * 4 + w, i2 = bi >> 1, s = bi & 1;
            gload16(comb + (size_t)(mbase + i2 * 16 + l15) * 1024 + k0 + s * 32 + quad * 8,
                    At + bi * 512);
            gload16(Wo16 + (size_t)(nbase + i2 * 16 + l15) * 1024 + k0 + s * 32 + quad * 8,
                    Bt + bi * 512);
        }
    };

    STAGE(0, 0);
    __syncthreads();
    for (int it = 0; it < 16; ++it) {
        const int cur = it & 1;
        if (it < 15) STAGE((it + 1) * 64, cur ^ 1);
        f16* At = (f16*)(sm + cur * 32768);
        f16* Bt = At + 8192;
#pragma unroll
        for (int s = 0; s < 2; ++s) {
            half8 a[4], bf[4];
#pragma unroll
            for (int i = 0; i < 4; ++i)
                a[i] = *reinterpret_cast<half8*>(At + ((ia + i) * 2 + s) * 512 + lane * 8);
#pragma unroll
            for (int j = 0; j < 4; ++j)
                bf[j] = *reinterpret_cast<half8*>(Bt + ((jb + j) * 2 + s) * 512 + lane * 8);
#pragma unroll
            for (int i = 0; i < 4; ++i)
#pragma unroll
                for (int j = 0; j < 4; ++j)
                    acc[i][j] = MFMA16(a[i], bf[j], acc[i][j]);
        }
        __syncthreads();
    }
    float* cf = (float*)sm;   // [64][132] fp32 padded
    for (int pass = 0; pass < 2; ++pass) {
        __syncthreads();
        if ((w & 1) == pass) {
#pragma unroll
            for (int i = 0; i < 4; ++i)
#pragma unroll
                for (int j = 0; j < 4; ++j)
#pragma unroll
                    for (int r = 0; r < 4; ++r)
                        cf[(i * 16 + quad * 4 + r) * 132 + wn + j * 16 + l15] = acc[i][j][r];
        }
        __syncthreads();
#pragma unroll
        for (int it = 0; it < 8; ++it) {
            int c = it * 256 + tid, row = c >> 5, c4 = (c & 31) << 2;
            __builtin_nontemporal_store(
                *reinterpret_cast<floatx4*>(cf + row * 132 + c4),
                reinterpret_cast<floatx4*>(out + (size_t)(mbase + pass * 64 + row) * 512 + nbase + c4));
        }
    }
}

extern "C" void kernel_launch(void* const* d_in, const int* in_sizes, int n_in,
                              void* d_out, int out_size, void* d_ws, size_t ws_size,
                              hipStream_t stream)
{
    const float* query = (const float*)d_in[0];
    const float* W_in  = (const float*)d_in[1];
    const float* W_out = (const float*)d_in[2];
    float* out = (float*)d_out;

    // ws layout (bytes):
    //   comb fp16 [32768][1024] (mix|q)        @ 0           (67,108,864)
    //   qT   fp16 [16][512][2048]              @ 67,108,864  (33,554,432)
    //   W16  fp16 [Wi 262144 | Wo 524288]      @ 100,663,296 (1,572,864)
    //   X    @ 102,236,160:
    //     q16 fp16 [16*2048*512] (33,554,432)  -- dead after k_qin
    //     Pd  fp16 [16][136][128][128]         @ XOFF        (71,303,168) aliases q16
    //     Mt  f32  [16][16][2048] (m_t -> F_t) @ +71,303,168 (2,097,152)
    //     Lt  f32  [16][16][2048] (l_t)        @ +73,400,320 (2,097,152)
    //   total = XOFF + 75.5MB = 177.7MB (ws proved >= 245MB in earlier rounds)
    const size_t XOFF = 102236160ull;
    f16* comb = (f16*)d_ws;
    f16* qT   = comb + (size_t)32768 * 1024;
    f16* W16  = qT + (size_t)16 * 512 * 2048;
    f16* q16  = (f16*)((char*)d_ws + XOFF);
    f16* Pd   = (f16*)((char*)d_ws + XOFF);
    float* Mt = (float*)((char*)d_ws + XOFF + 71303168ull);
    float* Lt = (float*)((char*)d_ws + XOFF + 73400320ull);

    k_cvt<<<17152, 256, 0, stream>>>(query, W_in, W_out, q16, W16);
    k_qin<<<1024, 256, 0, stream>>>(q16, W16, comb, qT);
    k_sgemmsm<<<dim3(16, 136), 256, 0, stream>>>(comb, Pd, Mt, Lt);
    k_stats<<<dim3(16, 8), 256, 0, stream>>>(Mt, Lt);
    k_pv<<<512, 256, 0, stream>>>(Pd, qT, comb, Mt);
    k_out<<<1024, 256, 0, stream>>>(comb, W16 + 262144, out);
}

// Round 10
// 404.487 us; speedup vs baseline: 1.3394x; 1.0615x over previous
//
#include <hip/hip_runtime.h>

typedef _Float16 f16;
typedef _Float16 half8 __attribute__((ext_vector_type(8)));
typedef _Float16 half4 __attribute__((ext_vector_type(4)));
typedef float floatx4 __attribute__((ext_vector_type(4)));

#define MFMA16(a, b, c) __builtin_amdgcn_mfma_f32_16x16x32_f16(a, b, c, 0, 0, 0)

// counted-vmcnt phase gate: wait until only the NEXT tile's 8 staging loads
// remain in flight (FIFO: the current tile's 8 are older -> retired first),
// fence the scheduler, then raw barrier (no implicit drain).
#define PHASE_WAIT_8()  do { asm volatile("s_waitcnt vmcnt(8)" ::: "memory"); \
    __builtin_amdgcn_sched_barrier(0); __builtin_amdgcn_s_barrier(); } while (0)
#define PHASE_WAIT_0()  do { asm volatile("s_waitcnt vmcnt(0)" ::: "memory"); \
    __builtin_amdgcn_sched_barrier(0); __builtin_amdgcn_s_barrier(); } while (0)

// async global->LDS, 16B per lane; LDS side = wave-uniform base + lane*16
__device__ __forceinline__ void gload16(const void* g, void* l) {
    __builtin_amdgcn_global_load_lds((const __attribute__((address_space(1))) void*)g,
                                     (__attribute__((address_space(3))) void*)l, 16, 0, 0);
}

// ---------------------------------------------------------------------------
// Kernel 0: convert query [16.8M], W_in [262144], W_out [524288] fp32 -> fp16
// ---------------------------------------------------------------------------
__global__ __launch_bounds__(256) void k_cvt(const float* __restrict__ query,
                                             const float* __restrict__ Wi,
                                             const float* __restrict__ Wo,
                                             f16* __restrict__ q16,
                                             f16* __restrict__ W16)
{
    int i = blockIdx.x * 256 + threadIdx.x;   // float4 index, 4390912 total
    const float4* src;
    f16* dst;
    if (i < 4194304) { src = (const float4*)query + i; dst = q16 + (size_t)i * 4; }
    else if (i < 4259840) { int j = i - 4194304; src = (const float4*)Wi + j; dst = W16 + (size_t)j * 4; }
    else { int j = i - 4259840; src = (const float4*)Wo + j; dst = W16 + 262144 + (size_t)j * 4; }
    float4 v = *src;
    half4 h = {(f16)v.x, (f16)v.y, (f16)v.z, (f16)v.w};
    *reinterpret_cast<half4*>(dst) = h;
}

// ---------------------------------------------------------------------------
// Kernel 1: q = q16 @ W16^T (fp16 gl_lds GEMM, BK=64, 128x128 tile).
// 1D grid 1024 with XCD swizzle. v6: counted-vmcnt pipeline — next tile's
// loads stay in flight across barriers (no per-iteration vmcnt(0) drain).
// ---------------------------------------------------------------------------
__global__ __launch_bounds__(256) void k_qin(const f16* __restrict__ q16,
                                             const f16* __restrict__ W16,
                                             f16* __restrict__ comb,
                                             f16* __restrict__ qT)
{
    __shared__ char sm[65536];
    const int tid = threadIdx.x, lane = tid & 63, w = tid >> 6;
    const int l15 = lane & 15, quad = lane >> 4;
    const int id = blockIdx.x, xcd = id & 7, u = id >> 3;
    const int mbase = (xcd * 32 + (u >> 2)) * 128;   // m-tile 0..255
    const int nbase = (u & 3) * 128;                 // n-tile 0..3
    const int wm = (w & 1) * 64, wn = (w >> 1) * 64;
    const int ia = wm >> 4, jb = wn >> 4;

    floatx4 acc[4][4];
#pragma unroll
    for (int i = 0; i < 4; ++i)
#pragma unroll
        for (int j = 0; j < 4; ++j) acc[i][j] = (floatx4)0.f;

    auto STAGE = [&](int k0, int bsel) {   // 8 gload16 per thread
        f16* At = (f16*)(sm + bsel * 32768);
        f16* Bt = At + 8192;
#pragma unroll
        for (int jr = 0; jr < 4; ++jr) {
            int bi = jr * 4 + w, i2 = bi >> 1, s = bi & 1;
            gload16(q16 + (size_t)(mbase + i2 * 16 + l15) * 512 + k0 + s * 32 + quad * 8, At + bi * 512);
            gload16(W16 + (size_t)(nbase + i2 * 16 + l15) * 512 + k0 + s * 32 + quad * 8, Bt + bi * 512);
        }
    };

    STAGE(0, 0);
    STAGE(64, 1);
    for (int it = 0; it < 8; ++it) {
        const int cur = it & 1;
        if (it < 7) PHASE_WAIT_8(); else PHASE_WAIT_0();
        f16* At = (f16*)(sm + cur * 32768);
        f16* Bt = At + 8192;
#pragma unroll
        for (int s = 0; s < 2; ++s) {
            half8 a[4], bf[4];
#pragma unroll
            for (int i = 0; i < 4; ++i)
                a[i] = *reinterpret_cast<half8*>(At + ((ia + i) * 2 + s) * 512 + lane * 8);
#pragma unroll
            for (int j = 0; j < 4; ++j)
                bf[j] = *reinterpret_cast<half8*>(Bt + ((jb + j) * 2 + s) * 512 + lane * 8);
#pragma unroll
            for (int i = 0; i < 4; ++i)
#pragma unroll
                for (int j = 0; j < 4; ++j)
                    acc[i][j] = MFMA16(a[i], bf[j], acc[i][j]);
        }
        __builtin_amdgcn_s_barrier();   // all waves done reading cur
        if (it + 2 < 8) STAGE((it + 2) * 64, cur);
    }
    const int bb = mbase >> 11, tb = mbase & 2047;
    f16* ct = (f16*)sm;   // phase A: row-major [128][136] (aliases dead staging bufs)
#pragma unroll
    for (int i = 0; i < 4; ++i)
#pragma unroll
        for (int j = 0; j < 4; ++j)
#pragma unroll
            for (int r = 0; r < 4; ++r)
                ct[(wm + i * 16 + quad * 4 + r) * 136 + wn + j * 16 + l15] = (f16)acc[i][j][r];
    __syncthreads();
#pragma unroll
    for (int it = 0; it < 8; ++it) {
        int c = it * 256 + tid, r = c >> 4, c8 = (c & 15) << 3;
        *reinterpret_cast<half8*>(comb + (size_t)(mbase + r) * 1024 + 512 + nbase + c8) =
            *reinterpret_cast<half8*>(ct + r * 136 + c8);
    }
    __syncthreads();
    // phase B: column-major [128 cols][136] — vectorized half4 dumps from acc
#pragma unroll
    for (int i = 0; i < 4; ++i)
#pragma unroll
        for (int j = 0; j < 4; ++j) {
            half4 h = {(f16)acc[i][j][0], (f16)acc[i][j][1], (f16)acc[i][j][2], (f16)acc[i][j][3]};
            *reinterpret_cast<half4*>(ct + (wn + j * 16 + l15) * 136 + wm + i * 16 + quad * 4) = h;
        }
    __syncthreads();
    // qT writes: 16 lanes share a d-row -> 256 B contiguous global segments
#pragma unroll
    for (int it = 0; it < 8; ++it) {
        int c = it * 256 + tid, dd = c >> 4, tc = (c & 15) << 3;
        *reinterpret_cast<half8*>(qT + ((size_t)bb * 512 + nbase + dd) * 2048 + tb + tc) =
            *reinterpret_cast<half8*>(ct + dd * 136 + tc);
    }
}

// ---------------------------------------------------------------------------
// Kernel 2: fused S-tile GEMM + PER-TILE softmax (parallel flash).
// One block per (b, causal tile), grid (16,136). v6: counted-vmcnt pipeline.
// Register epilogue: tile-local masked row max m_t, P_t = exp(S_t - m_t)
// fp16 (cached stores: re-read by k_pscale + k_pv on the same XCD), row
// sums l_t. Stats compose later (k_stats). S never touches HBM.
// ---------------------------------------------------------------------------
__global__ __launch_bounds__(256) void k_sgemmsm(const f16* __restrict__ comb,
                                                 f16* __restrict__ Pd,
                                                 float* __restrict__ Mt,
                                                 float* __restrict__ Lt)
{
    __shared__ char sm[65536];
    const int tid = threadIdx.x, lane = tid & 63, w = tid >> 6;
    const int l15 = lane & 15, quad = lane >> 4;
    const int wm = (w & 1) * 64, wn = (w >> 1) * 64;
    const int ia = wm >> 4, jb = wn >> 4;

    int bx = blockIdx.y, mt = 0;
    while ((mt + 1) * (mt + 2) / 2 <= bx) ++mt;
    const int nt = bx - mt * (mt + 1) / 2;
    const int b = blockIdx.x;   // grid (16,136): id&7 = b&7 -> batch/XCD pin
    const f16* qa = comb + ((size_t)b * 2048 + mt * 128) * 1024 + 512;
    const f16* qb = comb + ((size_t)b * 2048 + nt * 128) * 1024 + 512;

    floatx4 acc[4][4];
#pragma unroll
    for (int i = 0; i < 4; ++i)
#pragma unroll
        for (int j = 0; j < 4; ++j) acc[i][j] = (floatx4)0.f;

    auto STAGE = [&](int k0, int bsel) {   // 8 gload16 per thread
        f16* At = (f16*)(sm + bsel * 32768);
        f16* Bt = At + 8192;
#pragma unroll
        for (int jr = 0; jr < 4; ++jr) {
            int bi = jr * 4 + w, i2 = bi >> 1, s = bi & 1;
            gload16(qa + (size_t)(i2 * 16 + l15) * 1024 + k0 + s * 32 + quad * 8, At + bi * 512);
            gload16(qb + (size_t)(i2 * 16 + l15) * 1024 + k0 + s * 32 + quad * 8, Bt + bi * 512);
        }
    };

    STAGE(0, 0);
    STAGE(64, 1);
    for (int it = 0; it < 8; ++it) {
        const int cur = it & 1;
        if (it < 7) PHASE_WAIT_8(); else PHASE_WAIT_0();
        f16* At = (f16*)(sm + cur * 32768);
        f16* Bt = At + 8192;
#pragma unroll
        for (int s = 0; s < 2; ++s) {
            half8 a[4], bf[4];
#pragma unroll
            for (int i = 0; i < 4; ++i)
                a[i] = *reinterpret_cast<half8*>(At + ((ia + i) * 2 + s) * 512 + lane * 8);
#pragma unroll
            for (int j = 0; j < 4; ++j)
                bf[j] = *reinterpret_cast<half8*>(Bt + ((jb + j) * 2 + s) * 512 + lane * 8);
#pragma unroll
            for (int i = 0; i < 4; ++i)
#pragma unroll
                for (int j = 0; j < 4; ++j)
                    acc[i][j] = MFMA16(a[i], bf[j], acc[i][j]);
        }
        __builtin_amdgcn_s_barrier();
        if (it + 2 < 8) STAGE((it + 2) * 64, cur);
    }

    // ---- per-tile softmax epilogue ----
    const bool diag = (nt == mt);
    f16* ct = (f16*)sm;                   // [128][136], aliases dead staging
    float* redm = (float*)(sm + 40960);   // [4 waves][64 rows] partial max
    float* reds = (float*)(sm + 43008);   // [4 waves][64 rows] partial sum
    const int hb = w & 1;

    // masked wave-partial row max (reduce over j regs + l15 lanes)
    float wmax[4][4];
#pragma unroll
    for (int i = 0; i < 4; ++i)
#pragma unroll
        for (int r = 0; r < 4; ++r) {
            const int rowl = wm + i * 16 + quad * 4 + r;
            float mm = -1e38f;
#pragma unroll
            for (int j = 0; j < 4; ++j) {
                float v = acc[i][j][r];
                if (diag && (wn + j * 16 + l15) >= rowl) v = -1e38f;
                mm = fmaxf(mm, v);
            }
            mm = fmaxf(mm, __shfl_xor(mm, 1));
            mm = fmaxf(mm, __shfl_xor(mm, 2));
            mm = fmaxf(mm, __shfl_xor(mm, 4));
            mm = fmaxf(mm, __shfl_xor(mm, 8));
            wmax[i][r] = mm;
        }
    if (l15 == 0)
#pragma unroll
        for (int i = 0; i < 4; ++i)
#pragma unroll
            for (int r = 0; r < 4; ++r)
                redm[w * 64 + i * 16 + quad * 4 + r] = wmax[i][r];
    __syncthreads();

    // exp + P->ct + row partial sums
#pragma unroll
    for (int i = 0; i < 4; ++i)
#pragma unroll
        for (int r = 0; r < 4; ++r) {
            const int idx = i * 16 + quad * 4 + r;
            const int rowl = wm + idx;
            const float m = fmaxf(redm[hb * 64 + idx], redm[(hb + 2) * 64 + idx]);
            float ssum = 0.f;
#pragma unroll
            for (int j = 0; j < 4; ++j) {
                const int col = wn + j * 16 + l15;
                const bool valid = !diag || (col < rowl);
                float e = valid ? __expf(acc[i][j][r] - m) : 0.f;
                ssum += e;
                ct[rowl * 136 + col] = (f16)e;
            }
            ssum += __shfl_xor(ssum, 1);
            ssum += __shfl_xor(ssum, 2);
            ssum += __shfl_xor(ssum, 4);
            ssum += __shfl_xor(ssum, 8);
            wmax[i][r] = ssum;   // reuse as sum stash
        }
    if (l15 == 0)
#pragma unroll
        for (int i = 0; i < 4; ++i)
#pragma unroll
            for (int r = 0; r < 4; ++r)
                reds[w * 64 + i * 16 + quad * 4 + r] = wmax[i][r];
    __syncthreads();

    // m/l tables: one thread per row, contiguous 512B stores
    if (tid < 128) {
        const int h2 = tid >> 6, i2 = tid & 63;
        const float mm = fmaxf(redm[h2 * 64 + i2], redm[(h2 + 2) * 64 + i2]);
        const float ll = reds[h2 * 64 + i2] + reds[(h2 + 2) * 64 + i2];
        const size_t o = (((size_t)b * 16 + nt) << 11) + mt * 128 + tid;
        Mt[o] = mm;
        Lt[o] = ll;
    }
    // P' tile -> dense fp16 [b][tile][128][128], cached stores
    f16* Pt = Pd + ((size_t)(b * 136 + bx) << 14);
#pragma unroll
    for (int itp = 0; itp < 8; ++itp) {
        int c = itp * 256 + tid, r_ = c >> 4, c8 = (c & 15) << 3;
        *reinterpret_cast<half8*>(Pt + r_ * 128 + c8) =
            *reinterpret_cast<half8*>(ct + r_ * 136 + c8);
    }
}

// ---------------------------------------------------------------------------
// Kernel 3: combine per-tile stats -> per-tile scale factors, IN PLACE:
// F[b][t][row] = exp(m_t - M) / l  (0 if l==0, i.e. global row 0).
// M = max_t m_t, l = sum_t l_t * exp(m_t - M). One thread per row.
// ---------------------------------------------------------------------------
__global__ __launch_bounds__(256) void k_stats(float* Mt, const float* __restrict__ Lt)
{
    const int b = blockIdx.x, row = blockIdx.y * 256 + threadIdx.x;
    const int mtr = row >> 7;
    float mv[16], lv[16];
    for (int t = 0; t <= mtr; ++t) {
        const size_t o = (((size_t)b * 16 + t) << 11) + row;
        mv[t] = Mt[o];
        lv[t] = Lt[o];
    }
    float M = -1e38f;
    for (int t = 0; t <= mtr; ++t) M = fmaxf(M, mv[t]);
    float l = 0.f;
    for (int t = 0; t <= mtr; ++t) l += lv[t] * __expf(mv[t] - M);
    const float invl = (l > 0.f) ? 1.f / l : 0.f;
    for (int t = 0; t <= mtr; ++t)
        Mt[(((size_t)b * 16 + t) << 11) + row] = __expf(mv[t] - M) * invl;
}

// ---------------------------------------------------------------------------
// Kernel 3b (NEW): pre-scale P' rows by F -> P'' = final softmax weights.
// Removes the F-fold (and its pipeline-breaking Ft global loads) from
// k_pv's K-loop entirely. Grid (16,136) = same XCD pin as producer -> L2-hot.
// Tile (b, bx=(mt,nt)): row r scaled by F[b][nt][mt*128+r].
// ---------------------------------------------------------------------------
__global__ __launch_bounds__(256) void k_pscale(f16* __restrict__ Pd,
                                               const float* __restrict__ Ft)
{
    int bx = blockIdx.y, mt = 0;
    while ((mt + 1) * (mt + 2) / 2 <= bx) ++mt;
    const int nt = bx - mt * (mt + 1) / 2;
    const int b = blockIdx.x;
    const int tid = threadIdx.x;
    const int row = tid >> 1, c0 = (tid & 1) * 64;   // 2 threads/row, 64 halves each
    const float Fv = Ft[(((size_t)b * 16 + nt) << 11) + mt * 128 + row];
    f16* Pt = Pd + ((size_t)(b * 136 + bx) << 14) + (size_t)row * 128 + c0;
#pragma unroll
    for (int c = 0; c < 8; ++c) {
        half8 h = *reinterpret_cast<half8*>(Pt + c * 8);
#pragma unroll
        for (int e = 0; e < 8; ++e) h[e] = (f16)((float)h[e] * Fv);
        *reinterpret_cast<half8*>(Pt + c * 8) = h;
    }
}

// ---------------------------------------------------------------------------
// Kernel 4: mix = P'' @ qT — now a PURE GEMM (F pre-folded by k_pscale):
// single accumulator, no global loads in the K-loop, counted-vmcnt pipeline.
// Uniform-work pairing (mt=p with 15-p: 34 K-iters/block, 512 blocks).
// ---------------------------------------------------------------------------
__global__ __launch_bounds__(256) void k_pv(const f16* __restrict__ Pd,
                                            const f16* __restrict__ qT,
                                            f16* __restrict__ comb)
{
    __shared__ char sm[65536];
    const int tid = threadIdx.x, lane = tid & 63, w = tid >> 6;
    const int l15 = lane & 15, quad = lane >> 4;
    const int wm = (w & 1) * 64, wn = (w >> 1) * 64;
    const int ia = wm >> 4, jb = wn >> 4;
    const int id = blockIdx.x;
    const int p = id & 7, nb = (id >> 3) & 3, b = id >> 5;
    const f16* Pdb = Pd + ((size_t)b * 136 << 14);
    const f16* qTb = qT + ((size_t)b * 512 + nb * 128) * 2048;

    for (int t = 0; t < 2; ++t) {
        const int mt = t ? (15 - p) : p;
        const int tb0 = mt * (mt + 1) / 2;
        const int kit = (mt + 1) * 2;

        floatx4 acc[4][4];
#pragma unroll
        for (int i = 0; i < 4; ++i)
#pragma unroll
            for (int j = 0; j < 4; ++j) acc[i][j] = (floatx4)0.f;

        auto STAGE = [&](int it, int bsel) {   // 8 gload16 per thread
            f16* At = (f16*)(sm + bsel * 32768);
            f16* Bt = At + 8192;
            const int k0 = it * 64;
#pragma unroll
            for (int jr = 0; jr < 4; ++jr) {
                int bi = jr * 4 + w, i2 = bi >> 1, s = bi & 1;
                gload16(Pdb + ((size_t)(tb0 + (k0 >> 7)) << 14) + (size_t)(i2 * 16 + l15) * 128
                            + (k0 & 64) + s * 32 + quad * 8,
                        At + bi * 512);
                gload16(qTb + (size_t)(i2 * 16 + l15) * 2048 + k0 + s * 32 + quad * 8, Bt + bi * 512);
            }
        };

        STAGE(0, 0);
        STAGE(1, 1);
        for (int it = 0; it < kit; ++it) {
            const int cur = it & 1;
            if (it < kit - 1) PHASE_WAIT_8(); else PHASE_WAIT_0();
            f16* At = (f16*)(sm + cur * 32768);
            f16* Bt = At + 8192;
#pragma unroll
            for (int s = 0; s < 2; ++s) {
                half8 a[4], bf[4];
#pragma unroll
                for (int i = 0; i < 4; ++i)
                    a[i] = *reinterpret_cast<half8*>(At + ((ia + i) * 2 + s) * 512 + lane * 8);
#pragma unroll
                for (int j = 0; j < 4; ++j)
                    bf[j] = *reinterpret_cast<half8*>(Bt + ((jb + j) * 2 + s) * 512 + lane * 8);
#pragma unroll
                for (int i = 0; i < 4; ++i)
#pragma unroll
                    for (int j = 0; j < 4; ++j)
                        acc[i][j] = MFMA16(a[i], bf[j], acc[i][j]);
            }
            __builtin_amdgcn_s_barrier();   // all waves done reading cur
            if (it + 2 < kit) STAGE(it + 2, cur);
        }

        // epilogue: bounce via ct (aliases dead staging bufs), store comb
        f16* ct = (f16*)sm;
#pragma unroll
        for (int i = 0; i < 4; ++i)
#pragma unroll
            for (int j = 0; j < 4; ++j)
#pragma unroll
                for (int r = 0; r < 4; ++r)
                    ct[(wm + i * 16 + quad * 4 + r) * 136 + wn + j * 16 + l15] = (f16)acc[i][j][r];
        __syncthreads();
#pragma unroll
        for (int it = 0; it < 8; ++it) {
            int c = it * 256 + tid, r = c >> 4, c8 = (c & 15) << 3;
            *reinterpret_cast<half8*>(comb + ((size_t)b * 2048 + mt * 128 + r) * 1024 + nb * 128 + c8) =
                *reinterpret_cast<half8*>(ct + r * 136 + c8);
        }
        __syncthreads();   // ct reads done before next tile re-stages over it
    }
}

// ---------------------------------------------------------------------------
// Kernel 5: out = comb @ W_out^T (fp16 gl_lds GEMM, fp32 out). K=1024.
// 1D grid 1024, XCD swizzle. v6: counted-vmcnt pipeline.
// NT full-line output stores (out never re-read on device -> NT correct here).
// ---------------------------------------------------------------------------
__global__ __launch_bounds__(256) void k_out(const f16* __restrict__ comb,
                                             const f16* __restrict__ Wo16,
                                             float* __restrict__ out)
{
    __shared__ char sm[65536];
    const int tid = threadIdx.x, lane = tid & 63, w = tid >> 6;
    const int l15 = lane & 15, quad = lane >> 4;
    const int id = blockIdx.x, xcd = id & 7, u = id >> 3;
    const int mbase = (xcd * 32 + (u >> 2)) * 128;
    const int nbase = (u & 3) * 128;
    const int wm = (w & 1) * 64, wn = (w >> 1) * 64;
    const int ia = wm >> 4, jb = wn >> 4;

    floatx4 acc[4][4];
#pragma unroll
    for (int i = 0; i < 4; ++i)
#pragma unroll
        for (int j = 0; j < 4; ++j) acc[i][j] = (floatx4)0.f;

    auto STAGE = [&](int k0, int bsel) {   // 8 gload16 per thread
        f16* At = (f16*)(sm + bsel * 32768);
        f16* Bt = At + 8192;
#pragma unroll
        for (int jr = 0; jr < 4; ++jr) {
            int bi = jr * 4 + w, i2 = bi >> 1, s = bi & 1;
            gload16(comb + (size_t)(mbase + i2 * 16 + l15) * 1024 + k0 + s * 32 + quad * 8,
                    At + bi * 512);
            gload16(Wo16 + (size_t)(nbase + i2 * 16 + l15) * 1024 + k0 + s * 32 + quad * 8,
                    Bt + bi * 512);
        }
    };

    STAGE(0, 0);
    STAGE(64, 1);
    for (int it = 0; it < 16; ++it) {
        const int cur = it & 1;
        if (it < 15) PHASE_WAIT_8(); else PHASE_WAIT_0();
        f16* At = (f16*)(sm + cur * 32768);
        f16* Bt = At + 8192;
#pragma unroll
        for (int s = 0; s < 2; ++s) {
            half8 a[4], bf[4];
#pragma unroll
            for (int i = 0; i < 4; ++i)
                a[i] = *reinterpret_cast<half8*>(At + ((ia + i) * 2 + s) * 512 + lane * 8);
#pragma unroll
            for (int j = 0; j < 4; ++j)
                bf[j] = *reinterpret_cast<half8*>(Bt + ((jb + j) * 2 + s) * 512 + lane * 8);
#pragma unroll
            for (int i = 0; i < 4; ++i)
#pragma unroll
                for (int j = 0; j < 4; ++j)
                    acc[i][j] = MFMA16(a[i], bf[j], acc[i][j]);
        }
        __builtin_amdgcn_s_barrier();
        if (it + 2 < 16) STAGE((it + 2) * 64, cur);
    }
    float* cf = (float*)sm;   // [64][132] fp32 padded
    for (int pass = 0; pass < 2; ++pass) {
        __syncthreads();
        if ((w & 1) == pass) {
#pragma unroll
            for (int i = 0; i < 4; ++i)
#pragma unroll
                for (int j = 0; j < 4; ++j)
#pragma unroll
                    for (int r = 0; r < 4; ++r)
                        cf[(i * 16 + quad * 4 + r) * 132 + wn + j * 16 + l15] = acc[i][j][r];
        }
        __syncthreads();
#pragma unroll
        for (int it = 0; it < 8; ++it) {
            int c = it * 256 + tid, row = c >> 5, c4 = (c & 31) << 2;
            __builtin_nontemporal_store(
                *reinterpret_cast<floatx4*>(cf + row * 132 + c4),
                reinterpret_cast<floatx4*>(out + (size_t)(mbase + pass * 64 + row) * 512 + nbase + c4));
        }
    }
}

extern "C" void kernel_launch(void* const* d_in, const int* in_sizes, int n_in,
                              void* d_out, int out_size, void* d_ws, size_t ws_size,
                              hipStream_t stream)
{
    const float* query = (const float*)d_in[0];
    const float* W_in  = (const float*)d_in[1];
    const float* W_out = (const float*)d_in[2];
    float* out = (float*)d_out;

    // ws layout (bytes):
    //   comb fp16 [32768][1024] (mix|q)        @ 0           (67,108,864)
    //   qT   fp16 [16][512][2048]              @ 67,108,864  (33,554,432)
    //   W16  fp16 [Wi 262144 | Wo 524288]      @ 100,663,296 (1,572,864)
    //   X    @ 102,236,160:
    //     q16 fp16 [16*2048*512] (33,554,432)  -- dead after k_qin
    //     Pd  fp16 [16][136][128][128]         @ XOFF        (71,303,168) aliases q16
    //     Mt  f32  [16][16][2048] (m_t -> F_t) @ +71,303,168 (2,097,152)
    //     Lt  f32  [16][16][2048] (l_t)        @ +73,400,320 (2,097,152)
    const size_t XOFF = 102236160ull;
    f16* comb = (f16*)d_ws;
    f16* qT   = comb + (size_t)32768 * 1024;
    f16* W16  = qT + (size_t)16 * 512 * 2048;
    f16* q16  = (f16*)((char*)d_ws + XOFF);
    f16* Pd   = (f16*)((char*)d_ws + XOFF);
    float* Mt = (float*)((char*)d_ws + XOFF + 71303168ull);
    float* Lt = (float*)((char*)d_ws + XOFF + 73400320ull);

    k_cvt<<<17152, 256, 0, stream>>>(query, W_in, W_out, q16, W16);
    k_qin<<<1024, 256, 0, stream>>>(q16, W16, comb, qT);
    k_sgemmsm<<<dim3(16, 136), 256, 0, stream>>>(comb, Pd, Mt, Lt);
    k_stats<<<dim3(16, 8), 256, 0, stream>>>(Mt, Lt);
    k_pscale<<<dim3(16, 136), 256, 0, stream>>>(Pd, Mt);
    k_pv<<<512, 256, 0, stream>>>(Pd, qT, comb);
    k_out<<<1024, 256, 0, stream>>>(comb, W16 + 262144, out);
}